// Round 1
// baseline (265.382 us; speedup 1.0000x reference)
//
#include <hip/hip_runtime.h>
#include <hip/hip_bf16.h>

#define NB 2
#define NQ 20000
#define DM 64
#define NH 8
#define NL 5
#define NP 4
#define LIN 45109
#define FFN 1024

typedef __attribute__((ext_vector_type(8))) short short8;
typedef __attribute__((ext_vector_type(4))) float f32x4;

__device__ __forceinline__ float b2f(const __hip_bfloat16 h) { return __bfloat162float(h); }
__device__ __forceinline__ float lo16f(unsigned u) { return __uint_as_float(u << 16); }
__device__ __forceinline__ float hi16f(unsigned u) { return __uint_as_float(u & 0xffff0000u); }
__device__ __forceinline__ unsigned f2bf_bits(float x) {   // RNE round to bf16 bits
    unsigned u = __float_as_uint(x);
    return (u + 0x7FFFu + ((u >> 16) & 1u)) >> 16;
}

// ---- kernel 1: val = dvf @ Wv + bv via MFMA; 64 rows/block; 1 or 2 batches ----
__global__ void __launch_bounds__(256)
val_proj_kernel(const float* __restrict__ dvf,
                const float* __restrict__ Wv,
                const float* __restrict__ bv,
                __hip_bfloat16* __restrict__ valA,
                __hip_bfloat16* __restrict__ valB,
                int rows) {
    __shared__ __align__(16) __hip_bfloat16 wvp[8][64][8];  // B-frags: seg = nt*2+kc
    __shared__ __align__(16) __hip_bfloat16 ar[64][72];     // A rows, validated layout
    __shared__ __align__(16) float bvs[64];

    const int tid = threadIdx.x;
    const int lane = tid & 63;
    const int w = tid >> 6;
    const int m16 = lane & 15, qd = lane >> 4;
    const int row0 = blockIdx.x * 64;

    // pack Wv (64x64) into B-frag layout: B[k][n], k=(l>>4)*8+j + kc*32, n=nt*16+(l&15)
    for (int idx = tid; idx < 4096; idx += 256) {
        const int j = idx & 7;
        const int l = (idx >> 3) & 63;
        const int seg = idx >> 9;
        const int nt = seg >> 1, kc = seg & 1;
        const int n = nt * 16 + (l & 15);
        const int k = kc * 32 + (l >> 4) * 8 + j;
        wvp[seg][l][j] = __float2bfloat16(Wv[k * 64 + n]);
    }
    if (tid < 64) bvs[tid] = bv[tid];

    // wave w loads its 16 rows: lane -> row w*16+m16, cols qd*16..+15 (4x float4)
    {
        const int r = w * 16 + m16;
        const int grow = row0 + r;
        const int c0 = qd * 16;
        __hip_bfloat16* dst = &ar[r][c0];
        if (grow < rows) {
            const float4* src = (const float4*)&dvf[(size_t)grow * DM + c0];
#pragma unroll
            for (int t = 0; t < 4; t++) {
                const float4 v = src[t];
                dst[t * 4 + 0] = __float2bfloat16(v.x);
                dst[t * 4 + 1] = __float2bfloat16(v.y);
                dst[t * 4 + 2] = __float2bfloat16(v.z);
                dst[t * 4 + 3] = __float2bfloat16(v.w);
            }
        } else {
#pragma unroll
            for (int t = 0; t < 16; t++) dst[t] = __float2bfloat16(0.f);
        }
    }
    __syncthreads();

    // wave w computes M-tile w (rows w*16..+15): 4 ntiles x 2 kchunks
    f32x4 acc[4];
#pragma unroll
    for (int nt = 0; nt < 4; nt++) acc[nt] = (f32x4){0.f, 0.f, 0.f, 0.f};
#pragma unroll
    for (int kc = 0; kc < 2; kc++) {
        const short8 a = *(const short8*)&ar[w * 16 + m16][kc * 32 + qd * 8];
#pragma unroll
        for (int nt = 0; nt < 4; nt++) {
            const short8 b = *(const short8*)&wvp[nt * 2 + kc][lane][0];
            acc[nt] = __builtin_amdgcn_mfma_f32_16x16x32_bf16(a, b, acc[nt], 0, 0, 0);
        }
    }

    // store: D row = qd*4+r (voxel row), col = nt*16+m16 (channel)
#pragma unroll
    for (int r = 0; r < 4; r++) {
        const int gr = row0 + w * 16 + qd * 4 + r;
        if (gr < rows) {
            __hip_bfloat16* dst = (gr < LIN) ? (valA + (size_t)gr * DM)
                                             : (valB + (size_t)(gr - LIN) * DM);
#pragma unroll
            for (int nt = 0; nt < 4; nt++) {
                const int col = nt * 16 + m16;
                dst[col] = __float2bfloat16(acc[nt][r] + bvs[col]);
            }
        }
    }
}

// ---- kernel 2: pack W1/W2/[Wo|Wa]/Wout to bf16 MFMA B-fragment order ----
// B-frag 16x16x32: lane holds B[k=(lane>>4)*8+j][n=lane&15], j=0..7.
__global__ void pack_kernel(const float* __restrict__ W1, const float* __restrict__ W2,
                            const float* __restrict__ Wo, const float* __restrict__ Wa,
                            const float* __restrict__ Wout,
                            __hip_bfloat16* __restrict__ W1p, __hip_bfloat16* __restrict__ W2p,
                            __hip_bfloat16* __restrict__ Woap, __hip_bfloat16* __restrict__ Woutp) {
    const int t = blockIdx.x * 256 + threadIdx.x;
    const int lane = t & 63;
    const int m = lane & 15, qd = lane >> 4;
    const int seg = t >> 6;
    if (seg < 128) {                  // W1 (64x1024): 64 ntiles x 2 kchunks
        const int nt = seg >> 1, kc = seg & 1;
        const int n = nt * 16 + m, kb = kc * 32 + qd * 8;
        __hip_bfloat16* dst = W1p + ((size_t)seg * 64 + lane) * 8;
#pragma unroll
        for (int j = 0; j < 8; j++) dst[j] = __float2bfloat16(W1[(size_t)(kb + j) * FFN + n]);
    } else if (seg < 256) {           // W2 (1024x64): 4 ntiles x 32 kchunks
        const int sl = seg - 128;
        const int nt = sl >> 5, kc = sl & 31;
        const int n = nt * 16 + m, kb = kc * 32 + qd * 8;
        __hip_bfloat16* dst = W2p + ((size_t)sl * 64 + lane) * 8;
#pragma unroll
        for (int j = 0; j < 8; j++) dst[j] = __float2bfloat16(W2[(size_t)(kb + j) * DM + n]);
    } else if (seg < 316) {           // [Wo|Wa] (64x480): 30 ntiles x 2 kchunks
        const int sl = seg - 256;
        const int nt = sl >> 1, kc = sl & 1;
        const int n = nt * 16 + m, kb = kc * 32 + qd * 8;
        __hip_bfloat16* dst = Woap + ((size_t)sl * 64 + lane) * 8;
#pragma unroll
        for (int j = 0; j < 8; j++) {
            const int k = kb + j;
            const float v = (n < 320) ? Wo[(size_t)k * 320 + n] : Wa[(size_t)k * 160 + (n - 320)];
            dst[j] = __float2bfloat16(v);
        }
    } else if (seg < 324) {           // Wout (64x64): 4 ntiles x 2 kchunks (R8-validated)
        const int sl = seg - 316;
        const int nt = sl >> 1, kc = sl & 1;
        const int n = nt * 16 + m, kb = kc * 32 + qd * 8;
        __hip_bfloat16* dst = Woutp + ((size_t)sl * 64 + lane) * 8;
#pragma unroll
        for (int j = 0; j < 8; j++) dst[j] = __float2bfloat16(Wout[(size_t)(kb + j) * DM + n]);
    }
}

// ---- kernel 3: attn, 4 queries/block ----
// LDS trimmed to ~18.8 KB -> 8 blocks/CU (100% occupancy). Corner addresses are
// derived from a single clamped base (+64 / +Wl*64 per level, compile-time), so
// the int4 corner table is gone. Zero-weight OOB corners may read garbage that is
// multiplied by 0: reads below val land in the always-written pack region (finite
// bf16), reads above land in a zeroed guard pad (see kernel_launch memset).
__global__ void __launch_bounds__(256, 8)
attn4_kernel(const float* __restrict__ q_feat,
             const float* __restrict__ ref_pts,
             const float* __restrict__ q_pos,
             const __hip_bfloat16* __restrict__ Woap,
             const float* __restrict__ bo, const float* __restrict__ ba,
             const __hip_bfloat16* __restrict__ Woutp, const float* __restrict__ bout,
             const float* __restrict__ g1, const float* __restrict__ b1,
             const __hip_bfloat16* __restrict__ valA,
             const __hip_bfloat16* __restrict__ valB,
             int qoff,
             float* __restrict__ xout) {
    __shared__ __align__(16) __hip_bfloat16 qb[16][72];   // A-frag; rows 4-15 zero
    __shared__ __align__(16) float offs[4][321];
    __shared__ __align__(16) float aws[4][161];
    __shared__ __align__(16) float refs[4][2];
    __shared__ __align__(16) int   dbase[640];            // clamped base element offset
    __shared__ __align__(16) uint2 dwp[640];              // 4 bf16 weights packed
    __shared__ __align__(16) float xs4[4][64];            // phase-D output (pre-LN)

    const int tid = threadIdx.x;
    const int lane = tid & 63;
    const int w = tid >> 6;
    const int m16 = lane & 15, qd = lane >> 4;
    const int q0 = qoff + blockIdx.x * 4;                 // all 4 queries same batch
    const int qi = q0 + w;

    const int sz[NL]  = {184, 92, 46, 23, 12};
    const int lsi[NL] = {0, 33856, 42320, 44436, 44965};

    const __hip_bfloat16* valp = (q0 >= NQ) ? valB : valA;

    // ---- phase A: wave w owns query w ----
    const float qf = q_feat[(size_t)qi * DM + lane];
    const float qp = q_pos[(size_t)qi * DM + lane];
    qb[w][lane] = __float2bfloat16(qf + qp);
    for (int idx = tid; idx < 12 * 64; idx += 256)
        qb[4 + (idx >> 6)][idx & 63] = __float2bfloat16(0.f);
    if (tid < 8) refs[tid >> 1][tid & 1] = ref_pts[(size_t)(q0 + (tid >> 1)) * 2 + (tid & 1)];
    __syncthreads();

    // ---- phase B: [offs|aws] = q @ [Wo|Wa] + bias via MFMA (rows 0-3 valid) ----
    for (int nt = w; nt < 30; nt += 4) {
        f32x4 acc = {0.f, 0.f, 0.f, 0.f};
#pragma unroll
        for (int kc = 0; kc < 2; kc++) {
            const short8 a = *(const short8*)&qb[m16][kc * 32 + qd * 8];
            const short8 b = *(const short8*)(Woap + ((size_t)(nt * 2 + kc) * 64 + lane) * 8);
            acc = __builtin_amdgcn_mfma_f32_16x16x32_bf16(a, b, acc, 0, 0, 0);
        }
        if (qd == 0) {                       // rows 0..3 = queries 0..3
            const int n = nt * 16 + m16;
            if (n < 320) {
                const float bn = bo[n];
#pragma unroll
                for (int r = 0; r < 4; r++) offs[r][n] = acc[r] + bn;
            } else {
                const float bn = ba[n - 320];
#pragma unroll
                for (int r = 0; r < 4; r++) aws[r][n - 320] = acc[r] + bn;
            }
        }
    }
    __syncthreads();

    // ---- softmax per (query, head) over 20: 8 lanes per group, all 256 threads ----
    {
        const int g = tid >> 3;               // 0..31 = q*8 + h
        const int q = g >> 3, h = g & 7;
        const int j = tid & 7;
        float* p = &aws[q][h * 20];
        const float v0 = p[j], v1 = p[j + 8];
        const float v2 = (j < 4) ? p[j + 16] : -1e30f;
        float mx = fmaxf(fmaxf(v0, v1), v2);
        mx = fmaxf(mx, __shfl_xor(mx, 1, 8));
        mx = fmaxf(mx, __shfl_xor(mx, 2, 8));
        mx = fmaxf(mx, __shfl_xor(mx, 4, 8));
        const float e0 = __expf(v0 - mx), e1 = __expf(v1 - mx);
        const float e2 = (j < 4) ? __expf(v2 - mx) : 0.f;
        float s = e0 + e1 + e2;
        s += __shfl_xor(s, 1, 8);
        s += __shfl_xor(s, 2, 8);
        s += __shfl_xor(s, 4, 8);
        const float inv = 1.f / s;
        p[j] = e0 * inv;
        p[j + 8] = e1 * inv;
        if (j < 4) p[j + 16] = e2 * inv;
    }
    __syncthreads();

    // ---- precompute sample descriptors: s = ((q*5+l)*4+p)*8 + h ----
    // (ref + o/W)*W - 0.5 == fmaf(ref, W, o) - 0.5  -> no division.
    for (int s = tid; s < 640; s += 256) {
        const int h = s & 7;
        const int t2 = s >> 3;
        const int p = t2 & 3;
        const int t3 = t2 >> 2;           // q*5 + l
        const int l = t3 % 5;
        const int q = t3 / 5;
        const int Wl = sz[l];
        const float Wf = (float)Wl;
        const int st = lsi[l];
        const int c = ((h * 5 + l) * 4 + p) * 2;
        const float fx = fmaf(refs[q][0], Wf, offs[q][c]) - 0.5f;
        const float fy = fmaf(refs[q][1], Wf, offs[q][c + 1]) - 0.5f;
        const float x0f = floorf(fx), y0f = floorf(fy);
        const float wx = fx - x0f, wy = fy - y0f;
        const int x0 = (int)x0f, y0 = (int)y0f;
        const float aV = aws[q][h * 20 + l * 4 + p];
        const bool xin0 = (x0 >= 0) & (x0 < Wl);
        const bool xin1 = (x0 >= -1) & (x0 < Wl - 1);
        const bool yin0 = (y0 >= 0) & (y0 < Wl);
        const bool yin1 = (y0 >= -1) & (y0 < Wl - 1);
        const float w00 = (xin0 & yin0) ? (1.f - wx) * (1.f - wy) * aV : 0.f;
        const float w10 = (xin1 & yin0) ? wx * (1.f - wy) * aV : 0.f;
        const float w01 = (xin0 & yin1) ? (1.f - wx) * wy * aV : 0.f;
        const float w11 = (xin1 & yin1) ? wx * wy * aV : 0.f;
        // any descriptor with >=1 valid corner has base in [-11840, LIN*DM): clamp
        // only touches all-invalid (all-zero-weight) descriptors -> address safety.
        int base = (st + y0 * Wl + x0) * DM;
        base = base < -12160 ? -12160 : base;
        base = base > LIN * DM ? LIN * DM : base;
        dbase[s] = base;
        uint2 dw;
        dw.x = f2bf_bits(w00) | (f2bf_bits(w10) << 16);
        dw.y = f2bf_bits(w01) | (f2bf_bits(w11) << 16);
        dwp[s] = dw;
    }
    __syncthreads();

    // ---- phase C: sampling, wave = query w; lane = h*8 + d; result -> qb[w] ----
    {
        const int h = lane >> 3;
        const __hip_bfloat16* vbase = valp + lane;
        float a0 = 0.f, a1 = 0.f, a2 = 0.f, a3 = 0.f;   // 4 independent chains
        const int wl64[NL] = {184 * DM, 92 * DM, 46 * DM, 23 * DM, 12 * DM};
#pragma unroll
        for (int l = 0; l < NL; l++) {
#pragma unroll
            for (int p = 0; p < NP; p++) {
                const int idx = ((w * 5 + l) * 4 + p) * 8 + h;
                const int base = dbase[idx];
                const uint2 dw = dwp[idx];
                const __hip_bfloat16* r0 = vbase + base;
                const __hip_bfloat16* r1 = r0 + wl64[l];   // compile-time stride
                a0 = fmaf(lo16f(dw.x), b2f(r0[0]), a0);
                a1 = fmaf(hi16f(dw.x), b2f(r0[DM]), a1);
                a2 = fmaf(lo16f(dw.y), b2f(r1[0]), a2);
                a3 = fmaf(hi16f(dw.y), b2f(r1[DM]), a3);
            }
        }
        qb[w][lane] = __float2bfloat16((a0 + a1) + (a2 + a3));   // rows 4-15 stay zero
    }
    __syncthreads();

    // ---- phase D: attn @ Wout + bout via MFMA (wave w owns ntile w) ----
    {
        f32x4 acc = {0.f, 0.f, 0.f, 0.f};
#pragma unroll
        for (int kc = 0; kc < 2; kc++) {
            const short8 a = *(const short8*)&qb[m16][kc * 32 + qd * 8];
            const short8 b = *(const short8*)(Woutp + ((size_t)(w * 2 + kc) * 64 + lane) * 8);
            acc = __builtin_amdgcn_mfma_f32_16x16x32_bf16(a, b, acc, 0, 0, 0);
        }
        if (qd == 0) {
            const int n = w * 16 + m16;
            const float bn = bout[n];
#pragma unroll
            for (int r = 0; r < 4; r++) xs4[r][n] = acc[r] + bn;
        }
    }
    __syncthreads();

    // ---- LN1 (wave w = query w); residual qf; store x1 ----
    {
        const float xpre = qf + xs4[w][lane];
        float s = xpre, s2 = xpre * xpre;
#pragma unroll
        for (int o = 32; o >= 1; o >>= 1) {
            s += __shfl_xor(s, o, 64);
            s2 += __shfl_xor(s2, o, 64);
        }
        const float mean = s * (1.f / 64.f);
        const float var = s2 * (1.f / 64.f) - mean * mean;
        const float xn = (xpre - mean) * rsqrtf(var + 1e-5f);
        xout[(size_t)qi * DM + lane] = xn * g1[lane] + b1[lane];
    }
}

// ---- kernel 4: FFN via MFMA, 32 queries/block, hidden in 4 quarters; 29.7 KB LDS ----
__global__ void __launch_bounds__(256)
ffn_kernel(const __hip_bfloat16* __restrict__ W1p, const float* __restrict__ bff1,
           const __hip_bfloat16* __restrict__ W2p, const float* __restrict__ bff2,
           const float* __restrict__ g2, const float* __restrict__ b2,
           float* __restrict__ io) {
    __shared__ __align__(16) __hip_bfloat16 xb[32][72];    // 4608 B
    __shared__ __align__(16) __hip_bfloat16 hb[32][264];   // 16896 B (256 cols + pad)
    __shared__ __align__(16) float yr[32][64];             // 8192 B

    const int tid = threadIdx.x;
    const int lane = tid & 63;
    const int w = tid >> 6;
    const int m16 = lane & 15, qd = lane >> 4;
    const int q0 = blockIdx.x * 32;

    // ---- load x1: thread t -> query t>>3, cols (t&7)*8 .. +7 (bf16 only; f32 reloaded at LN) ----
    {
        const int q = tid >> 3, i = tid & 7;
        const float4 v0 = *(const float4*)&io[(size_t)(q0 + q) * DM + i * 8];
        const float4 v1 = *(const float4*)&io[(size_t)(q0 + q) * DM + i * 8 + 4];
        __hip_bfloat16* xp = &xb[q][i * 8];
        xp[0] = __float2bfloat16(v0.x); xp[1] = __float2bfloat16(v0.y);
        xp[2] = __float2bfloat16(v0.z); xp[3] = __float2bfloat16(v0.w);
        xp[4] = __float2bfloat16(v1.x); xp[5] = __float2bfloat16(v1.y);
        xp[6] = __float2bfloat16(v1.z); xp[7] = __float2bfloat16(v1.w);
    }
    __syncthreads();

    f32x4 yacc[2];
    yacc[0] = (f32x4){0.f, 0.f, 0.f, 0.f};
    yacc[1] = (f32x4){0.f, 0.f, 0.f, 0.f};

#pragma unroll
    for (int qtr = 0; qtr < 4; qtr++) {
        // GEMM1 quarter: hidden cols [qtr*256, +256); wave w does ntiles qtr*16 + w + 4*ti
#pragma unroll
        for (int ti = 0; ti < 4; ti++) {
            const int nt = qtr * 16 + w + ti * 4;
            f32x4 acc[2];
            acc[0] = (f32x4){0.f, 0.f, 0.f, 0.f};
            acc[1] = (f32x4){0.f, 0.f, 0.f, 0.f};
#pragma unroll
            for (int kc = 0; kc < 2; kc++) {
                const short8 b = *(const short8*)(W1p + ((size_t)(nt * 2 + kc) * 64 + lane) * 8);
#pragma unroll
                for (int mt = 0; mt < 2; mt++) {
                    const short8 a = *(const short8*)&xb[mt * 16 + m16][kc * 32 + qd * 8];
                    acc[mt] = __builtin_amdgcn_mfma_f32_16x16x32_bf16(a, b, acc[mt], 0, 0, 0);
                }
            }
            const int ncol = (nt - qtr * 16) * 16 + m16;   // 0..255
            const float bn = bff1[nt * 16 + m16];
#pragma unroll
            for (int mt = 0; mt < 2; mt++)
#pragma unroll
                for (int r = 0; r < 4; r++)
                    hb[mt * 16 + qd * 4 + r][ncol] = __float2bfloat16(fmaxf(acc[mt][r] + bn, 0.f));
        }
        __syncthreads();
        // GEMM2 partial: wave w owns y-ntile w; this quarter's 8 kchunks
#pragma unroll
        for (int kc2 = 0; kc2 < 8; kc2++) {
            const short8 b = *(const short8*)(W2p + ((size_t)(w * 32 + qtr * 8 + kc2) * 64 + lane) * 8);
#pragma unroll
            for (int mt = 0; mt < 2; mt++) {
                const short8 a = *(const short8*)&hb[mt * 16 + m16][kc2 * 32 + qd * 8];
                yacc[mt] = __builtin_amdgcn_mfma_f32_16x16x32_bf16(a, b, yacc[mt], 0, 0, 0);
            }
        }
        __syncthreads();   // hb consumed before next quarter overwrites
    }

    // ---- Y + bff2 (x1 residual re-read from io at LN stage) ----
    {
        const int n = w * 16 + m16;
        const float bn = bff2[n];
#pragma unroll
        for (int mt = 0; mt < 2; mt++)
#pragma unroll
            for (int r = 0; r < 4; r++) {
                const int mm = mt * 16 + qd * 4 + r;
                yr[mm][n] = yacc[mt][r] + bn;
            }
    }
    __syncthreads();

    // ---- LN2 + store: thread t -> query t>>3, cols (t&7)*8..+7; 8-lane reduce ----
    {
        const int q = tid >> 3, i = tid & 7;
        const float4 x0 = *(const float4*)&io[(size_t)(q0 + q) * DM + i * 8];
        const float4 x1 = *(const float4*)&io[(size_t)(q0 + q) * DM + i * 8 + 4];
        float4 v0 = *(const float4*)&yr[q][i * 8];
        float4 v1 = *(const float4*)&yr[q][i * 8 + 4];
        v0.x += x0.x; v0.y += x0.y; v0.z += x0.z; v0.w += x0.w;
        v1.x += x1.x; v1.y += x1.y; v1.z += x1.z; v1.w += x1.w;
        float s = v0.x + v0.y + v0.z + v0.w + v1.x + v1.y + v1.z + v1.w;
        float s2 = v0.x * v0.x + v0.y * v0.y + v0.z * v0.z + v0.w * v0.w
                 + v1.x * v1.x + v1.y * v1.y + v1.z * v1.z + v1.w * v1.w;
#pragma unroll
        for (int o = 4; o >= 1; o >>= 1) { s += __shfl_xor(s, o, 64); s2 += __shfl_xor(s2, o, 64); }
        const float mean = s * (1.f / 64.f);
        const float var = s2 * (1.f / 64.f) - mean * mean;
        const float rstd = rsqrtf(var + 1e-5f);
        const float4 ga = *(const float4*)&g2[i * 8];
        const float4 gb = *(const float4*)&g2[i * 8 + 4];
        const float4 ba4 = *(const float4*)&b2[i * 8];
        const float4 bb4 = *(const float4*)&b2[i * 8 + 4];
        float4 o0, o1;
        o0.x = (v0.x - mean) * rstd * ga.x + ba4.x;
        o0.y = (v0.y - mean) * rstd * ga.y + ba4.y;
        o0.z = (v0.z - mean) * rstd * ga.z + ba4.z;
        o0.w = (v0.w - mean) * rstd * ga.w + ba4.w;
        o1.x = (v1.x - mean) * rstd * gb.x + bb4.x;
        o1.y = (v1.y - mean) * rstd * gb.y + bb4.y;
        o1.z = (v1.z - mean) * rstd * gb.z + bb4.z;
        o1.w = (v1.w - mean) * rstd * gb.w + bb4.w;
        *(float4*)&io[(size_t)(q0 + q) * DM + i * 8] = o0;
        *(float4*)&io[(size_t)(q0 + q) * DM + i * 8 + 4] = o1;
    }
}

extern "C" void kernel_launch(void* const* d_in, const int* in_sizes, int n_in,
                              void* d_out, int out_size, void* d_ws, size_t ws_size,
                              hipStream_t stream) {
    const int B0 = (in_sizes[4] >= 4096) ? 4 : 6;   // int side-inputs present -> 6
    const float* q_feat = (const float*)d_in[0];
    const float* dvf    = (const float*)d_in[1];
    const float* refp   = (const float*)d_in[2];
    const float* q_pos  = (const float*)d_in[3];
    const float* Wv   = (const float*)d_in[B0 + 0];
    const float* bv   = (const float*)d_in[B0 + 1];
    const float* Wo   = (const float*)d_in[B0 + 2];
    const float* bo   = (const float*)d_in[B0 + 3];
    const float* Wa   = (const float*)d_in[B0 + 4];
    const float* ba   = (const float*)d_in[B0 + 5];
    const float* Wout = (const float*)d_in[B0 + 6];
    const float* bout = (const float*)d_in[B0 + 7];
    const float* g1   = (const float*)d_in[B0 + 8];
    const float* b1   = (const float*)d_in[B0 + 9];
    const float* W1   = (const float*)d_in[B0 + 10];
    const float* bff1 = (const float*)d_in[B0 + 11];
    const float* W2   = (const float*)d_in[B0 + 12];
    const float* bff2 = (const float*)d_in[B0 + 13];
    const float* g2   = (const float*)d_in[B0 + 14];
    const float* b2   = (const float*)d_in[B0 + 15];
    float* out = (float*)d_out;

    const size_t val_elems = (size_t)LIN * DM;
    const size_t pack_elems = (size_t)(128 + 128 + 60 + 8) * 64 * 8;   // 165888 bf16
    const size_t PAD_ELEMS = 12288;    // guard pad: derived OOB corners read here x0
    const bool dbuf = ws_size >= (pack_elems + 2 * val_elems + PAD_ELEMS) * sizeof(__hip_bfloat16);

    __hip_bfloat16* W1p = (__hip_bfloat16*)d_ws;
    __hip_bfloat16* W2p = W1p + (size_t)128 * 64 * 8;
    __hip_bfloat16* Woap = W2p + (size_t)128 * 64 * 8;
    __hip_bfloat16* Woutp = Woap + (size_t)60 * 64 * 8;
    __hip_bfloat16* val0 = W1p + pack_elems;
    __hip_bfloat16* val1 = dbuf ? val0 + val_elems : val0;

    // zero the guard pad after the value buffer(s): uninitialized workspace could
    // hold NaN bf16 patterns, and 0-weight x NaN = NaN. (graph-capture-safe)
    __hip_bfloat16* pad_ptr = val1 + val_elems;
    hipMemsetAsync(pad_ptr, 0, PAD_ELEMS * sizeof(__hip_bfloat16), stream);

    pack_kernel<<<81, 256, 0, stream>>>(W1, W2, Wo, Wa, Wout, W1p, W2p, Woap, Woutp);

    if (dbuf) {
        val_proj_kernel<<<(2 * LIN + 63) / 64, 256, 0, stream>>>(
            dvf, Wv, bv, val0, val1, 2 * LIN);
        attn4_kernel<<<(NB * NQ) / 4, 256, 0, stream>>>(
            q_feat, refp, q_pos, Woap, bo, ba, Woutp, bout, g1, b1,
            val0, val1, 0, out);
    } else {
        for (int b = 0; b < NB; b++) {
            val_proj_kernel<<<(LIN + 63) / 64, 256, 0, stream>>>(
                dvf + (size_t)b * val_elems, Wv, bv, val0, val0, LIN);
            attn4_kernel<<<NQ / 4, 256, 0, stream>>>(
                q_feat, refp, q_pos, Woap, bo, ba, Woutp, bout, g1, b1,
                val0, val0, b * NQ, out);
        }
    }
    ffn_kernel<<<(NB * NQ) / 32, 256, 0, stream>>>(W1p, bff1, W2p, bff2, g2, b2, out);
}

// Round 2
// 251.259 us; speedup vs baseline: 1.0562x; 1.0562x over previous
//
#include <hip/hip_runtime.h>
#include <hip/hip_bf16.h>

#define NB 2
#define NQ 20000
#define DM 64
#define NH 8
#define NL 5
#define NP 4
#define LIN 45109
#define FFN 1024

typedef __attribute__((ext_vector_type(8))) short short8;
typedef __attribute__((ext_vector_type(4))) float f32x4;

__device__ __forceinline__ float b2f(const __hip_bfloat16 h) { return __bfloat162float(h); }
__device__ __forceinline__ float lo16f(unsigned u) { return __uint_as_float(u << 16); }
__device__ __forceinline__ float hi16f(unsigned u) { return __uint_as_float(u & 0xffff0000u); }
__device__ __forceinline__ unsigned f2bf_bits(float x) {   // RNE round to bf16 bits
    unsigned u = __float_as_uint(x);
    return (u + 0x7FFFu + ((u >> 16) & 1u)) >> 16;
}

// ---- kernel 1: val = dvf @ Wv + bv via MFMA; head-major output [h][voxel][8] ----
__global__ void __launch_bounds__(256)
val_proj_kernel(const float* __restrict__ dvf,
                const float* __restrict__ Wv,
                const float* __restrict__ bv,
                __hip_bfloat16* __restrict__ valA,
                __hip_bfloat16* __restrict__ valB,
                int rows) {
    __shared__ __align__(16) __hip_bfloat16 wvp[8][64][8];  // B-frags: seg = nt*2+kc
    __shared__ __align__(16) __hip_bfloat16 ar[64][72];     // A rows, validated layout
    __shared__ __align__(16) float bvs[64];

    const int tid = threadIdx.x;
    const int lane = tid & 63;
    const int w = tid >> 6;
    const int m16 = lane & 15, qd = lane >> 4;
    const int row0 = blockIdx.x * 64;

    // pack Wv (64x64) into B-frag layout: B[k][n], k=(l>>4)*8+j + kc*32, n=nt*16+(l&15)
    for (int idx = tid; idx < 4096; idx += 256) {
        const int j = idx & 7;
        const int l = (idx >> 3) & 63;
        const int seg = idx >> 9;
        const int nt = seg >> 1, kc = seg & 1;
        const int n = nt * 16 + (l & 15);
        const int k = kc * 32 + (l >> 4) * 8 + j;
        wvp[seg][l][j] = __float2bfloat16(Wv[k * 64 + n]);
    }
    if (tid < 64) bvs[tid] = bv[tid];

    // wave w loads its 16 rows: lane -> row w*16+m16, cols qd*16..+15 (4x float4)
    {
        const int r = w * 16 + m16;
        const int grow = row0 + r;
        const int c0 = qd * 16;
        __hip_bfloat16* dst = &ar[r][c0];
        if (grow < rows) {
            const float4* src = (const float4*)&dvf[(size_t)grow * DM + c0];
#pragma unroll
            for (int t = 0; t < 4; t++) {
                const float4 v = src[t];
                dst[t * 4 + 0] = __float2bfloat16(v.x);
                dst[t * 4 + 1] = __float2bfloat16(v.y);
                dst[t * 4 + 2] = __float2bfloat16(v.z);
                dst[t * 4 + 3] = __float2bfloat16(v.w);
            }
        } else {
#pragma unroll
            for (int t = 0; t < 16; t++) dst[t] = __float2bfloat16(0.f);
        }
    }
    __syncthreads();

    // wave w computes M-tile w (rows w*16..+15): 4 ntiles x 2 kchunks
    f32x4 acc[4];
#pragma unroll
    for (int nt = 0; nt < 4; nt++) acc[nt] = (f32x4){0.f, 0.f, 0.f, 0.f};
#pragma unroll
    for (int kc = 0; kc < 2; kc++) {
        const short8 a = *(const short8*)&ar[w * 16 + m16][kc * 32 + qd * 8];
#pragma unroll
        for (int nt = 0; nt < 4; nt++) {
            const short8 b = *(const short8*)&wvp[nt * 2 + kc][lane][0];
            acc[nt] = __builtin_amdgcn_mfma_f32_16x16x32_bf16(a, b, acc[nt], 0, 0, 0);
        }
    }

    // store head-major: element (h, vox, d) at ((h*LIN + vox)*8 + d)
#pragma unroll
    for (int r = 0; r < 4; r++) {
        const int gr = row0 + w * 16 + qd * 4 + r;
        if (gr < rows) {
            const int vr = (gr < LIN) ? gr : gr - LIN;
            __hip_bfloat16* dst = (gr < LIN) ? valA : valB;
#pragma unroll
            for (int nt = 0; nt < 4; nt++) {
                const int c = nt * 16 + m16;                  // channel 0..63
                dst[((size_t)(c >> 3) * LIN + vr) * 8 + (c & 7)] =
                    __float2bfloat16(acc[nt][r] + bvs[c]);
            }
        }
    }
}

// ---- kernel 2: pack W1/W2/[Wo|Wa]/Wout to bf16 MFMA B-fragment order ----
// B-frag 16x16x32: lane holds B[k=(lane>>4)*8+j][n=lane&15], j=0..7.
__global__ void pack_kernel(const float* __restrict__ W1, const float* __restrict__ W2,
                            const float* __restrict__ Wo, const float* __restrict__ Wa,
                            const float* __restrict__ Wout,
                            __hip_bfloat16* __restrict__ W1p, __hip_bfloat16* __restrict__ W2p,
                            __hip_bfloat16* __restrict__ Woap, __hip_bfloat16* __restrict__ Woutp) {
    const int t = blockIdx.x * 256 + threadIdx.x;
    const int lane = t & 63;
    const int m = lane & 15, qd = lane >> 4;
    const int seg = t >> 6;
    if (seg < 128) {                  // W1 (64x1024): 64 ntiles x 2 kchunks
        const int nt = seg >> 1, kc = seg & 1;
        const int n = nt * 16 + m, kb = kc * 32 + qd * 8;
        __hip_bfloat16* dst = W1p + ((size_t)seg * 64 + lane) * 8;
#pragma unroll
        for (int j = 0; j < 8; j++) dst[j] = __float2bfloat16(W1[(size_t)(kb + j) * FFN + n]);
    } else if (seg < 256) {           // W2 (1024x64): 4 ntiles x 32 kchunks
        const int sl = seg - 128;
        const int nt = sl >> 5, kc = sl & 31;
        const int n = nt * 16 + m, kb = kc * 32 + qd * 8;
        __hip_bfloat16* dst = W2p + ((size_t)sl * 64 + lane) * 8;
#pragma unroll
        for (int j = 0; j < 8; j++) dst[j] = __float2bfloat16(W2[(size_t)(kb + j) * DM + n]);
    } else if (seg < 316) {           // [Wo|Wa] (64x480): 30 ntiles x 2 kchunks
        const int sl = seg - 256;
        const int nt = sl >> 1, kc = sl & 1;
        const int n = nt * 16 + m, kb = kc * 32 + qd * 8;
        __hip_bfloat16* dst = Woap + ((size_t)sl * 64 + lane) * 8;
#pragma unroll
        for (int j = 0; j < 8; j++) {
            const int k = kb + j;
            const float v = (n < 320) ? Wo[(size_t)k * 320 + n] : Wa[(size_t)k * 160 + (n - 320)];
            dst[j] = __float2bfloat16(v);
        }
    } else if (seg < 324) {           // Wout (64x64): 4 ntiles x 2 kchunks (R8-validated)
        const int sl = seg - 316;
        const int nt = sl >> 1, kc = sl & 1;
        const int n = nt * 16 + m, kb = kc * 32 + qd * 8;
        __hip_bfloat16* dst = Woutp + ((size_t)sl * 64 + lane) * 8;
#pragma unroll
        for (int j = 0; j < 8; j++) dst[j] = __float2bfloat16(Wout[(size_t)(kb + j) * DM + n]);
    }
}

// ---- kernel 3: attn, 4 queries/block; value is head-major [h][voxel][8] ----
// ~18.8 KB LDS -> 8 blocks/CU. Corner addresses derived from one clamped voxel
// base (x-pair = +8 elems contiguous, y-pair = +Wl*8, compile-time). Zero-weight
// OOB corners may read garbage multiplied by 0: below -> pack region (finite),
// above -> next batch / zeroed guard pad (see kernel_launch memset).
__global__ void __launch_bounds__(256, 8)
attn4_kernel(const float* __restrict__ q_feat,
             const float* __restrict__ ref_pts,
             const float* __restrict__ q_pos,
             const __hip_bfloat16* __restrict__ Woap,
             const float* __restrict__ bo, const float* __restrict__ ba,
             const __hip_bfloat16* __restrict__ Woutp, const float* __restrict__ bout,
             const float* __restrict__ g1, const float* __restrict__ b1,
             const __hip_bfloat16* __restrict__ valA,
             const __hip_bfloat16* __restrict__ valB,
             int qoff,
             float* __restrict__ xout) {
    __shared__ __align__(16) __hip_bfloat16 qb[16][72];   // A-frag; rows 4-15 zero
    __shared__ __align__(16) float offs[4][321];
    __shared__ __align__(16) float aws[4][161];
    __shared__ __align__(16) float refs[4][2];
    __shared__ __align__(16) int   dbase[640];            // clamped vox*8 offset
    __shared__ __align__(16) uint2 dwp[640];              // 4 bf16 weights packed
    __shared__ __align__(16) float xs4[4][64];            // phase-D output (pre-LN)

    const int tid = threadIdx.x;
    const int lane = tid & 63;
    const int w = tid >> 6;
    const int m16 = lane & 15, qd = lane >> 4;
    const int q0 = qoff + blockIdx.x * 4;                 // all 4 queries same batch
    const int qi = q0 + w;

    const int sz[NL]  = {184, 92, 46, 23, 12};
    const int lsi[NL] = {0, 33856, 42320, 44436, 44965};

    const __hip_bfloat16* valp = (q0 >= NQ) ? valB : valA;

    // ---- phase A: wave w owns query w ----
    const float qf = q_feat[(size_t)qi * DM + lane];
    const float qp = q_pos[(size_t)qi * DM + lane];
    qb[w][lane] = __float2bfloat16(qf + qp);
    for (int idx = tid; idx < 12 * 64; idx += 256)
        qb[4 + (idx >> 6)][idx & 63] = __float2bfloat16(0.f);
    if (tid < 8) refs[tid >> 1][tid & 1] = ref_pts[(size_t)(q0 + (tid >> 1)) * 2 + (tid & 1)];
    __syncthreads();

    // ---- phase B: [offs|aws] = q @ [Wo|Wa] + bias via MFMA (rows 0-3 valid) ----
    for (int nt = w; nt < 30; nt += 4) {
        f32x4 acc = {0.f, 0.f, 0.f, 0.f};
#pragma unroll
        for (int kc = 0; kc < 2; kc++) {
            const short8 a = *(const short8*)&qb[m16][kc * 32 + qd * 8];
            const short8 b = *(const short8*)(Woap + ((size_t)(nt * 2 + kc) * 64 + lane) * 8);
            acc = __builtin_amdgcn_mfma_f32_16x16x32_bf16(a, b, acc, 0, 0, 0);
        }
        if (qd == 0) {                       // rows 0..3 = queries 0..3
            const int n = nt * 16 + m16;
            if (n < 320) {
                const float bn = bo[n];
#pragma unroll
                for (int r = 0; r < 4; r++) offs[r][n] = acc[r] + bn;
            } else {
                const float bn = ba[n - 320];
#pragma unroll
                for (int r = 0; r < 4; r++) aws[r][n - 320] = acc[r] + bn;
            }
        }
    }
    __syncthreads();

    // ---- softmax per (query, head) over 20: 8 lanes per group, all 256 threads ----
    {
        const int g = tid >> 3;               // 0..31 = q*8 + h
        const int q = g >> 3, h = g & 7;
        const int j = tid & 7;
        float* p = &aws[q][h * 20];
        const float v0 = p[j], v1 = p[j + 8];
        const float v2 = (j < 4) ? p[j + 16] : -1e30f;
        float mx = fmaxf(fmaxf(v0, v1), v2);
        mx = fmaxf(mx, __shfl_xor(mx, 1, 8));
        mx = fmaxf(mx, __shfl_xor(mx, 2, 8));
        mx = fmaxf(mx, __shfl_xor(mx, 4, 8));
        const float e0 = __expf(v0 - mx), e1 = __expf(v1 - mx);
        const float e2 = (j < 4) ? __expf(v2 - mx) : 0.f;
        float s = e0 + e1 + e2;
        s += __shfl_xor(s, 1, 8);
        s += __shfl_xor(s, 2, 8);
        s += __shfl_xor(s, 4, 8);
        const float inv = 1.f / s;
        p[j] = e0 * inv;
        p[j + 8] = e1 * inv;
        if (j < 4) p[j + 16] = e2 * inv;
    }
    __syncthreads();

    // ---- precompute sample descriptors: s = ((q*5+l)*4+p)*8 + h ----
    // (ref + o/W)*W - 0.5 == fmaf(ref, W, o) - 0.5  -> no division.
    for (int s = tid; s < 640; s += 256) {
        const int h = s & 7;
        const int t2 = s >> 3;
        const int p = t2 & 3;
        const int t3 = t2 >> 2;           // q*5 + l
        const int l = t3 % 5;
        const int q = t3 / 5;
        const int Wl = sz[l];
        const float Wf = (float)Wl;
        const int st = lsi[l];
        const int c = ((h * 5 + l) * 4 + p) * 2;
        const float fx = fmaf(refs[q][0], Wf, offs[q][c]) - 0.5f;
        const float fy = fmaf(refs[q][1], Wf, offs[q][c + 1]) - 0.5f;
        const float x0f = floorf(fx), y0f = floorf(fy);
        const float wx = fx - x0f, wy = fy - y0f;
        const int x0 = (int)x0f, y0 = (int)y0f;
        const float aV = aws[q][h * 20 + l * 4 + p];
        const bool xin0 = (x0 >= 0) & (x0 < Wl);
        const bool xin1 = (x0 >= -1) & (x0 < Wl - 1);
        const bool yin0 = (y0 >= 0) & (y0 < Wl);
        const bool yin1 = (y0 >= -1) & (y0 < Wl - 1);
        const float w00 = (xin0 & yin0) ? (1.f - wx) * (1.f - wy) * aV : 0.f;
        const float w10 = (xin1 & yin0) ? wx * (1.f - wy) * aV : 0.f;
        const float w01 = (xin0 & yin1) ? (1.f - wx) * wy * aV : 0.f;
        const float w11 = (xin1 & yin1) ? wx * wy * aV : 0.f;
        // any descriptor with >=1 valid corner has vox in [-185, LIN): clamp only
        // touches all-invalid (all-zero-weight) descriptors -> address safety.
        int base = (st + y0 * Wl + x0) * 8;     // vox*8 (head-major element units)
        base = base < -1520 ? -1520 : base;
        base = base > LIN * 8 ? LIN * 8 : base;
        dbase[s] = base;
        uint2 dw;
        dw.x = f2bf_bits(w00) | (f2bf_bits(w10) << 16);
        dw.y = f2bf_bits(w01) | (f2bf_bits(w11) << 16);
        dwp[s] = dw;
    }
    __syncthreads();

    // ---- phase C: sampling, wave = query w; lane = h*8 + d; head-major gathers ----
    {
        const int h = lane >> 3, d = lane & 7;
        const __hip_bfloat16* vbase = valp + (size_t)h * (LIN * 8) + d;
        float a0 = 0.f, a1 = 0.f, a2 = 0.f, a3 = 0.f;   // 4 independent chains
        const int wl8[NL] = {184 * 8, 92 * 8, 46 * 8, 23 * 8, 12 * 8};
#pragma unroll
        for (int l = 0; l < NL; l++) {
#pragma unroll
            for (int p = 0; p < NP; p++) {
                const int idx = ((w * 5 + l) * 4 + p) * 8 + h;
                const int base = dbase[idx];
                const uint2 dw = dwp[idx];
                const __hip_bfloat16* r0 = vbase + base;
                const __hip_bfloat16* r1 = r0 + wl8[l];   // compile-time stride
                a0 = fmaf(lo16f(dw.x), b2f(r0[0]), a0);
                a1 = fmaf(hi16f(dw.x), b2f(r0[8]), a1);
                a2 = fmaf(lo16f(dw.y), b2f(r1[0]), a2);
                a3 = fmaf(hi16f(dw.y), b2f(r1[8]), a3);
            }
        }
        qb[w][lane] = __float2bfloat16((a0 + a1) + (a2 + a3));   // rows 4-15 stay zero
    }
    __syncthreads();

    // ---- phase D: attn @ Wout + bout via MFMA (wave w owns ntile w) ----
    {
        f32x4 acc = {0.f, 0.f, 0.f, 0.f};
#pragma unroll
        for (int kc = 0; kc < 2; kc++) {
            const short8 a = *(const short8*)&qb[m16][kc * 32 + qd * 8];
            const short8 b = *(const short8*)(Woutp + ((size_t)(w * 2 + kc) * 64 + lane) * 8);
            acc = __builtin_amdgcn_mfma_f32_16x16x32_bf16(a, b, acc, 0, 0, 0);
        }
        if (qd == 0) {
            const int n = w * 16 + m16;
            const float bn = bout[n];
#pragma unroll
            for (int r = 0; r < 4; r++) xs4[r][n] = acc[r] + bn;
        }
    }
    __syncthreads();

    // ---- LN1 (wave w = query w); residual qf; store x1 ----
    {
        const float xpre = qf + xs4[w][lane];
        float s = xpre, s2 = xpre * xpre;
#pragma unroll
        for (int o = 32; o >= 1; o >>= 1) {
            s += __shfl_xor(s, o, 64);
            s2 += __shfl_xor(s2, o, 64);
        }
        const float mean = s * (1.f / 64.f);
        const float var = s2 * (1.f / 64.f) - mean * mean;
        const float xn = (xpre - mean) * rsqrtf(var + 1e-5f);
        xout[(size_t)qi * DM + lane] = xn * g1[lane] + b1[lane];
    }
}

// ---- kernel 4: FFN via MFMA, 32 queries/block, hidden in 4 quarters; 29.7 KB LDS ----
__global__ void __launch_bounds__(256)
ffn_kernel(const __hip_bfloat16* __restrict__ W1p, const float* __restrict__ bff1,
           const __hip_bfloat16* __restrict__ W2p, const float* __restrict__ bff2,
           const float* __restrict__ g2, const float* __restrict__ b2,
           float* __restrict__ io) {
    __shared__ __align__(16) __hip_bfloat16 xb[32][72];    // 4608 B
    __shared__ __align__(16) __hip_bfloat16 hb[32][264];   // 16896 B (256 cols + pad)
    __shared__ __align__(16) float yr[32][64];             // 8192 B

    const int tid = threadIdx.x;
    const int lane = tid & 63;
    const int w = tid >> 6;
    const int m16 = lane & 15, qd = lane >> 4;
    const int q0 = blockIdx.x * 32;

    // ---- load x1: thread t -> query t>>3, cols (t&7)*8 .. +7 (bf16 only; f32 reloaded at LN) ----
    {
        const int q = tid >> 3, i = tid & 7;
        const float4 v0 = *(const float4*)&io[(size_t)(q0 + q) * DM + i * 8];
        const float4 v1 = *(const float4*)&io[(size_t)(q0 + q) * DM + i * 8 + 4];
        __hip_bfloat16* xp = &xb[q][i * 8];
        xp[0] = __float2bfloat16(v0.x); xp[1] = __float2bfloat16(v0.y);
        xp[2] = __float2bfloat16(v0.z); xp[3] = __float2bfloat16(v0.w);
        xp[4] = __float2bfloat16(v1.x); xp[5] = __float2bfloat16(v1.y);
        xp[6] = __float2bfloat16(v1.z); xp[7] = __float2bfloat16(v1.w);
    }
    __syncthreads();

    f32x4 yacc[2];
    yacc[0] = (f32x4){0.f, 0.f, 0.f, 0.f};
    yacc[1] = (f32x4){0.f, 0.f, 0.f, 0.f};

#pragma unroll
    for (int qtr = 0; qtr < 4; qtr++) {
        // GEMM1 quarter: hidden cols [qtr*256, +256); wave w does ntiles qtr*16 + w + 4*ti
#pragma unroll
        for (int ti = 0; ti < 4; ti++) {
            const int nt = qtr * 16 + w + ti * 4;
            f32x4 acc[2];
            acc[0] = (f32x4){0.f, 0.f, 0.f, 0.f};
            acc[1] = (f32x4){0.f, 0.f, 0.f, 0.f};
#pragma unroll
            for (int kc = 0; kc < 2; kc++) {
                const short8 b = *(const short8*)(W1p + ((size_t)(nt * 2 + kc) * 64 + lane) * 8);
#pragma unroll
                for (int mt = 0; mt < 2; mt++) {
                    const short8 a = *(const short8*)&xb[mt * 16 + m16][kc * 32 + qd * 8];
                    acc[mt] = __builtin_amdgcn_mfma_f32_16x16x32_bf16(a, b, acc[mt], 0, 0, 0);
                }
            }
            const int ncol = (nt - qtr * 16) * 16 + m16;   // 0..255
            const float bn = bff1[nt * 16 + m16];
#pragma unroll
            for (int mt = 0; mt < 2; mt++)
#pragma unroll
                for (int r = 0; r < 4; r++)
                    hb[mt * 16 + qd * 4 + r][ncol] = __float2bfloat16(fmaxf(acc[mt][r] + bn, 0.f));
        }
        __syncthreads();
        // GEMM2 partial: wave w owns y-ntile w; this quarter's 8 kchunks
#pragma unroll
        for (int kc2 = 0; kc2 < 8; kc2++) {
            const short8 b = *(const short8*)(W2p + ((size_t)(w * 32 + qtr * 8 + kc2) * 64 + lane) * 8);
#pragma unroll
            for (int mt = 0; mt < 2; mt++) {
                const short8 a = *(const short8*)&hb[mt * 16 + m16][kc2 * 32 + qd * 8];
                yacc[mt] = __builtin_amdgcn_mfma_f32_16x16x32_bf16(a, b, yacc[mt], 0, 0, 0);
            }
        }
        __syncthreads();   // hb consumed before next quarter overwrites
    }

    // ---- Y + bff2 (x1 residual re-read from io at LN stage) ----
    {
        const int n = w * 16 + m16;
        const float bn = bff2[n];
#pragma unroll
        for (int mt = 0; mt < 2; mt++)
#pragma unroll
            for (int r = 0; r < 4; r++) {
                const int mm = mt * 16 + qd * 4 + r;
                yr[mm][n] = yacc[mt][r] + bn;
            }
    }
    __syncthreads();

    // ---- LN2 + store: thread t -> query t>>3, cols (t&7)*8..+7; 8-lane reduce ----
    {
        const int q = tid >> 3, i = tid & 7;
        const float4 x0 = *(const float4*)&io[(size_t)(q0 + q) * DM + i * 8];
        const float4 x1 = *(const float4*)&io[(size_t)(q0 + q) * DM + i * 8 + 4];
        float4 v0 = *(const float4*)&yr[q][i * 8];
        float4 v1 = *(const float4*)&yr[q][i * 8 + 4];
        v0.x += x0.x; v0.y += x0.y; v0.z += x0.z; v0.w += x0.w;
        v1.x += x1.x; v1.y += x1.y; v1.z += x1.z; v1.w += x1.w;
        float s = v0.x + v0.y + v0.z + v0.w + v1.x + v1.y + v1.z + v1.w;
        float s2 = v0.x * v0.x + v0.y * v0.y + v0.z * v0.z + v0.w * v0.w
                 + v1.x * v1.x + v1.y * v1.y + v1.z * v1.z + v1.w * v1.w;
#pragma unroll
        for (int o = 4; o >= 1; o >>= 1) { s += __shfl_xor(s, o, 64); s2 += __shfl_xor(s2, o, 64); }
        const float mean = s * (1.f / 64.f);
        const float var = s2 * (1.f / 64.f) - mean * mean;
        const float rstd = rsqrtf(var + 1e-5f);
        const float4 ga = *(const float4*)&g2[i * 8];
        const float4 gb = *(const float4*)&g2[i * 8 + 4];
        const float4 ba4 = *(const float4*)&b2[i * 8];
        const float4 bb4 = *(const float4*)&b2[i * 8 + 4];
        float4 o0, o1;
        o0.x = (v0.x - mean) * rstd * ga.x + ba4.x;
        o0.y = (v0.y - mean) * rstd * ga.y + ba4.y;
        o0.z = (v0.z - mean) * rstd * ga.z + ba4.z;
        o0.w = (v0.w - mean) * rstd * ga.w + ba4.w;
        o1.x = (v1.x - mean) * rstd * gb.x + bb4.x;
        o1.y = (v1.y - mean) * rstd * gb.y + bb4.y;
        o1.z = (v1.z - mean) * rstd * gb.z + bb4.z;
        o1.w = (v1.w - mean) * rstd * gb.w + bb4.w;
        *(float4*)&io[(size_t)(q0 + q) * DM + i * 8] = o0;
        *(float4*)&io[(size_t)(q0 + q) * DM + i * 8 + 4] = o1;
    }
}

extern "C" void kernel_launch(void* const* d_in, const int* in_sizes, int n_in,
                              void* d_out, int out_size, void* d_ws, size_t ws_size,
                              hipStream_t stream) {
    const int B0 = (in_sizes[4] >= 4096) ? 4 : 6;   // int side-inputs present -> 6
    const float* q_feat = (const float*)d_in[0];
    const float* dvf    = (const float*)d_in[1];
    const float* refp   = (const float*)d_in[2];
    const float* q_pos  = (const float*)d_in[3];
    const float* Wv   = (const float*)d_in[B0 + 0];
    const float* bv   = (const float*)d_in[B0 + 1];
    const float* Wo   = (const float*)d_in[B0 + 2];
    const float* bo   = (const float*)d_in[B0 + 3];
    const float* Wa   = (const float*)d_in[B0 + 4];
    const float* ba   = (const float*)d_in[B0 + 5];
    const float* Wout = (const float*)d_in[B0 + 6];
    const float* bout = (const float*)d_in[B0 + 7];
    const float* g1   = (const float*)d_in[B0 + 8];
    const float* b1   = (const float*)d_in[B0 + 9];
    const float* W1   = (const float*)d_in[B0 + 10];
    const float* bff1 = (const float*)d_in[B0 + 11];
    const float* W2   = (const float*)d_in[B0 + 12];
    const float* bff2 = (const float*)d_in[B0 + 13];
    const float* g2   = (const float*)d_in[B0 + 14];
    const float* b2   = (const float*)d_in[B0 + 15];
    float* out = (float*)d_out;

    const size_t val_elems = (size_t)LIN * DM;
    const size_t pack_elems = (size_t)(128 + 128 + 60 + 8) * 64 * 8;   // 165888 bf16
    const size_t PAD_ELEMS = 12288;    // guard pad: derived OOB corners read here x0
    const bool dbuf = ws_size >= (pack_elems + 2 * val_elems + PAD_ELEMS) * sizeof(__hip_bfloat16);

    __hip_bfloat16* W1p = (__hip_bfloat16*)d_ws;
    __hip_bfloat16* W2p = W1p + (size_t)128 * 64 * 8;
    __hip_bfloat16* Woap = W2p + (size_t)128 * 64 * 8;
    __hip_bfloat16* Woutp = Woap + (size_t)60 * 64 * 8;
    __hip_bfloat16* val0 = W1p + pack_elems;
    __hip_bfloat16* val1 = dbuf ? val0 + val_elems : val0;

    // zero the guard pad after the value buffer(s): uninitialized workspace could
    // hold NaN bf16 patterns, and 0-weight x NaN = NaN. (graph-capture-safe)
    __hip_bfloat16* pad_ptr = val1 + val_elems;
    hipMemsetAsync(pad_ptr, 0, PAD_ELEMS * sizeof(__hip_bfloat16), stream);

    pack_kernel<<<81, 256, 0, stream>>>(W1, W2, Wo, Wa, Wout, W1p, W2p, Woap, Woutp);

    if (dbuf) {
        val_proj_kernel<<<(2 * LIN + 63) / 64, 256, 0, stream>>>(
            dvf, Wv, bv, val0, val1, 2 * LIN);
        attn4_kernel<<<(NB * NQ) / 4, 256, 0, stream>>>(
            q_feat, refp, q_pos, Woap, bo, ba, Woutp, bout, g1, b1,
            val0, val1, 0, out);
    } else {
        for (int b = 0; b < NB; b++) {
            val_proj_kernel<<<(LIN + 63) / 64, 256, 0, stream>>>(
                dvf + (size_t)b * val_elems, Wv, bv, val0, val0, LIN);
            attn4_kernel<<<NQ / 4, 256, 0, stream>>>(
                q_feat, refp, q_pos, Woap, bo, ba, Woutp, bout, g1, b1,
                val0, val0, b * NQ, out);
        }
    }
    ffn_kernel<<<(NB * NQ) / 32, 256, 0, stream>>>(W1p, bff1, W2p, bff2, g2, b2, out);
}

// Round 3
// 236.387 us; speedup vs baseline: 1.1227x; 1.0629x over previous
//
#include <hip/hip_runtime.h>
#include <hip/hip_bf16.h>

#define NB 2
#define NQ 20000
#define DM 64
#define NH 8
#define NL 5
#define NP 4
#define LIN 45109
#define FFN 1024

typedef __attribute__((ext_vector_type(8))) short short8;
typedef __attribute__((ext_vector_type(4))) float f32x4;

__device__ __forceinline__ float b2f(const __hip_bfloat16 h) { return __bfloat162float(h); }
__device__ __forceinline__ float lo16f(unsigned u) { return __uint_as_float(u << 16); }
__device__ __forceinline__ float hi16f(unsigned u) { return __uint_as_float(u & 0xffff0000u); }
__device__ __forceinline__ unsigned f2bf_bits(float x) {   // RNE round to bf16 bits
    unsigned u = __float_as_uint(x);
    return (u + 0x7FFFu + ((u >> 16) & 1u)) >> 16;
}

// ---- kernel 1: val = dvf @ Wv + bv via MFMA; head-major output [h][voxel][8] ----
__global__ void __launch_bounds__(256)
val_proj_kernel(const float* __restrict__ dvf,
                const float* __restrict__ Wv,
                const float* __restrict__ bv,
                __hip_bfloat16* __restrict__ valA,
                __hip_bfloat16* __restrict__ valB,
                int rows) {
    __shared__ __align__(16) __hip_bfloat16 wvp[8][64][8];  // B-frags: seg = nt*2+kc
    __shared__ __align__(16) __hip_bfloat16 ar[64][72];     // A rows, validated layout
    __shared__ __align__(16) float bvs[64];

    const int tid = threadIdx.x;
    const int lane = tid & 63;
    const int w = tid >> 6;
    const int m16 = lane & 15, qd = lane >> 4;
    const int row0 = blockIdx.x * 64;

    // pack Wv (64x64) into B-frag layout: B[k][n], k=(l>>4)*8+j + kc*32, n=nt*16+(l&15)
    for (int idx = tid; idx < 4096; idx += 256) {
        const int j = idx & 7;
        const int l = (idx >> 3) & 63;
        const int seg = idx >> 9;
        const int nt = seg >> 1, kc = seg & 1;
        const int n = nt * 16 + (l & 15);
        const int k = kc * 32 + (l >> 4) * 8 + j;
        wvp[seg][l][j] = __float2bfloat16(Wv[k * 64 + n]);
    }
    if (tid < 64) bvs[tid] = bv[tid];

    // wave w loads its 16 rows: lane -> row w*16+m16, cols qd*16..+15 (4x float4)
    {
        const int r = w * 16 + m16;
        const int grow = row0 + r;
        const int c0 = qd * 16;
        __hip_bfloat16* dst = &ar[r][c0];
        if (grow < rows) {
            const float4* src = (const float4*)&dvf[(size_t)grow * DM + c0];
#pragma unroll
            for (int t = 0; t < 4; t++) {
                const float4 v = src[t];
                dst[t * 4 + 0] = __float2bfloat16(v.x);
                dst[t * 4 + 1] = __float2bfloat16(v.y);
                dst[t * 4 + 2] = __float2bfloat16(v.z);
                dst[t * 4 + 3] = __float2bfloat16(v.w);
            }
        } else {
#pragma unroll
            for (int t = 0; t < 16; t++) dst[t] = __float2bfloat16(0.f);
        }
    }
    __syncthreads();

    // wave w computes M-tile w (rows w*16..+15): 4 ntiles x 2 kchunks
    f32x4 acc[4];
#pragma unroll
    for (int nt = 0; nt < 4; nt++) acc[nt] = (f32x4){0.f, 0.f, 0.f, 0.f};
#pragma unroll
    for (int kc = 0; kc < 2; kc++) {
        const short8 a = *(const short8*)&ar[w * 16 + m16][kc * 32 + qd * 8];
#pragma unroll
        for (int nt = 0; nt < 4; nt++) {
            const short8 b = *(const short8*)&wvp[nt * 2 + kc][lane][0];
            acc[nt] = __builtin_amdgcn_mfma_f32_16x16x32_bf16(a, b, acc[nt], 0, 0, 0);
        }
    }

    // store head-major: element (h, vox, d) at ((h*LIN + vox)*8 + d)
#pragma unroll
    for (int r = 0; r < 4; r++) {
        const int gr = row0 + w * 16 + qd * 4 + r;
        if (gr < rows) {
            const int vr = (gr < LIN) ? gr : gr - LIN;
            __hip_bfloat16* dst = (gr < LIN) ? valA : valB;
#pragma unroll
            for (int nt = 0; nt < 4; nt++) {
                const int c = nt * 16 + m16;                  // channel 0..63
                dst[((size_t)(c >> 3) * LIN + vr) * 8 + (c & 7)] =
                    __float2bfloat16(acc[nt][r] + bvs[c]);
            }
        }
    }
}

// ---- kernel 2: pack W1/W2/[Wo|Wa]/Wout to bf16 MFMA B-fragment order ----
// B-frag 16x16x32: lane holds B[k=(lane>>4)*8+j][n=lane&15], j=0..7.
__global__ void pack_kernel(const float* __restrict__ W1, const float* __restrict__ W2,
                            const float* __restrict__ Wo, const float* __restrict__ Wa,
                            const float* __restrict__ Wout,
                            __hip_bfloat16* __restrict__ W1p, __hip_bfloat16* __restrict__ W2p,
                            __hip_bfloat16* __restrict__ Woap, __hip_bfloat16* __restrict__ Woutp) {
    const int t = blockIdx.x * 256 + threadIdx.x;
    const int lane = t & 63;
    const int m = lane & 15, qd = lane >> 4;
    const int seg = t >> 6;
    if (seg < 128) {                  // W1 (64x1024): 64 ntiles x 2 kchunks
        const int nt = seg >> 1, kc = seg & 1;
        const int n = nt * 16 + m, kb = kc * 32 + qd * 8;
        __hip_bfloat16* dst = W1p + ((size_t)seg * 64 + lane) * 8;
#pragma unroll
        for (int j = 0; j < 8; j++) dst[j] = __float2bfloat16(W1[(size_t)(kb + j) * FFN + n]);
    } else if (seg < 256) {           // W2 (1024x64): 4 ntiles x 32 kchunks
        const int sl = seg - 128;
        const int nt = sl >> 5, kc = sl & 31;
        const int n = nt * 16 + m, kb = kc * 32 + qd * 8;
        __hip_bfloat16* dst = W2p + ((size_t)sl * 64 + lane) * 8;
#pragma unroll
        for (int j = 0; j < 8; j++) dst[j] = __float2bfloat16(W2[(size_t)(kb + j) * DM + n]);
    } else if (seg < 316) {           // [Wo|Wa] (64x480): 30 ntiles x 2 kchunks
        const int sl = seg - 256;
        const int nt = sl >> 1, kc = sl & 1;
        const int n = nt * 16 + m, kb = kc * 32 + qd * 8;
        __hip_bfloat16* dst = Woap + ((size_t)sl * 64 + lane) * 8;
#pragma unroll
        for (int j = 0; j < 8; j++) {
            const int k = kb + j;
            const float v = (n < 320) ? Wo[(size_t)k * 320 + n] : Wa[(size_t)k * 160 + (n - 320)];
            dst[j] = __float2bfloat16(v);
        }
    } else if (seg < 324) {           // Wout (64x64): 4 ntiles x 2 kchunks (R8-validated)
        const int sl = seg - 316;
        const int nt = sl >> 1, kc = sl & 1;
        const int n = nt * 16 + m, kb = kc * 32 + qd * 8;
        __hip_bfloat16* dst = Woutp + ((size_t)sl * 64 + lane) * 8;
#pragma unroll
        for (int j = 0; j < 8; j++) dst[j] = __float2bfloat16(Wout[(size_t)(kb + j) * DM + n]);
    }
}

// ---- kernel 3: attn, 4 queries/block; value head-major [h][voxel][8] ----
// Phase C vectorized: lane (h,j) loads whole 16B corner segments (dwordx4),
// corner c = j&3 fixed per lane, sample = 2k + (j>>2); 10 loads/thread in
// flight vs 80 scalar gathers/wave. Per-sample descriptor is one 16B LDS
// struct {b0, b1, w4}; channel sums reduced across the 8 lanes of a head
// group via shfl_xor butterfly. LDS 20288B -> 8 blocks/CU.
// Zero-weight OOB corners may read garbage multiplied by 0: below -> pack
// region (finite), above -> zeroed guard pad (see kernel_launch memset).
__global__ void __launch_bounds__(256, 8)
attn4_kernel(const float* __restrict__ q_feat,
             const float* __restrict__ ref_pts,
             const float* __restrict__ q_pos,
             const __hip_bfloat16* __restrict__ Woap,
             const float* __restrict__ bo, const float* __restrict__ ba,
             const __hip_bfloat16* __restrict__ Woutp, const float* __restrict__ bout,
             const float* __restrict__ g1, const float* __restrict__ b1,
             const __hip_bfloat16* __restrict__ valA,
             const __hip_bfloat16* __restrict__ valB,
             int qoff,
             float* __restrict__ xout) {
    __shared__ __align__(16) __hip_bfloat16 qb[16][72];   // A-frag; rows 4-15 zero
    __shared__ __align__(16) float offs[4][321];          // phase-D xs4 aliases this
    __shared__ __align__(16) float aws[4][161];
    __shared__ __align__(16) float refs[4][2];
    __shared__ __align__(16) int4  dsc[640];              // {b0, b1, w01, w23} per (q,s,h)

    float (*xs4)[64] = (float(*)[64])offs;                // offs dead after descriptors

    const int tid = threadIdx.x;
    const int lane = tid & 63;
    const int w = tid >> 6;
    const int m16 = lane & 15, qd = lane >> 4;
    const int q0 = qoff + blockIdx.x * 4;                 // all 4 queries same batch
    const int qi = q0 + w;

    const int sz[NL]  = {184, 92, 46, 23, 12};
    const int lsi[NL] = {0, 33856, 42320, 44436, 44965};

    const __hip_bfloat16* valp = (q0 >= NQ) ? valB : valA;

    // ---- phase A: wave w owns query w ----
    const float qf = q_feat[(size_t)qi * DM + lane];
    const float qp = q_pos[(size_t)qi * DM + lane];
    qb[w][lane] = __float2bfloat16(qf + qp);
    for (int idx = tid; idx < 12 * 64; idx += 256)
        qb[4 + (idx >> 6)][idx & 63] = __float2bfloat16(0.f);
    if (tid < 8) refs[tid >> 1][tid & 1] = ref_pts[(size_t)(q0 + (tid >> 1)) * 2 + (tid & 1)];
    __syncthreads();

    // ---- phase B: [offs|aws] = q @ [Wo|Wa] + bias via MFMA (rows 0-3 valid) ----
    for (int nt = w; nt < 30; nt += 4) {
        f32x4 acc = {0.f, 0.f, 0.f, 0.f};
#pragma unroll
        for (int kc = 0; kc < 2; kc++) {
            const short8 a = *(const short8*)&qb[m16][kc * 32 + qd * 8];
            const short8 b = *(const short8*)(Woap + ((size_t)(nt * 2 + kc) * 64 + lane) * 8);
            acc = __builtin_amdgcn_mfma_f32_16x16x32_bf16(a, b, acc, 0, 0, 0);
        }
        if (qd == 0) {                       // rows 0..3 = queries 0..3
            const int n = nt * 16 + m16;
            if (n < 320) {
                const float bn = bo[n];
#pragma unroll
                for (int r = 0; r < 4; r++) offs[r][n] = acc[r] + bn;
            } else {
                const float bn = ba[n - 320];
#pragma unroll
                for (int r = 0; r < 4; r++) aws[r][n - 320] = acc[r] + bn;
            }
        }
    }
    __syncthreads();

    // ---- softmax per (query, head) over 20: 8 lanes per group, all 256 threads ----
    {
        const int g = tid >> 3;               // 0..31 = q*8 + h
        const int q = g >> 3, h = g & 7;
        const int j = tid & 7;
        float* p = &aws[q][h * 20];
        const float v0 = p[j], v1 = p[j + 8];
        const float v2 = (j < 4) ? p[j + 16] : -1e30f;
        float mx = fmaxf(fmaxf(v0, v1), v2);
        mx = fmaxf(mx, __shfl_xor(mx, 1, 8));
        mx = fmaxf(mx, __shfl_xor(mx, 2, 8));
        mx = fmaxf(mx, __shfl_xor(mx, 4, 8));
        const float e0 = __expf(v0 - mx), e1 = __expf(v1 - mx);
        const float e2 = (j < 4) ? __expf(v2 - mx) : 0.f;
        float s = e0 + e1 + e2;
        s += __shfl_xor(s, 1, 8);
        s += __shfl_xor(s, 2, 8);
        s += __shfl_xor(s, 4, 8);
        const float inv = 1.f / s;
        p[j] = e0 * inv;
        p[j + 8] = e1 * inv;
        if (j < 4) p[j + 16] = e2 * inv;
    }
    __syncthreads();

    // ---- precompute sample descriptors: s = ((q*5+l)*4+p)*8 + h ----
    // (ref + o/W)*W - 0.5 == fmaf(ref, W, o) - 0.5  -> no division.
    for (int s = tid; s < 640; s += 256) {
        const int h = s & 7;
        const int t2 = s >> 3;
        const int p = t2 & 3;
        const int t3 = t2 >> 2;           // q*5 + l
        const int l = t3 % 5;
        const int q = t3 / 5;
        const int Wl = sz[l];
        const float Wf = (float)Wl;
        const int st = lsi[l];
        const int c = ((h * 5 + l) * 4 + p) * 2;
        const float fx = fmaf(refs[q][0], Wf, offs[q][c]) - 0.5f;
        const float fy = fmaf(refs[q][1], Wf, offs[q][c + 1]) - 0.5f;
        const float x0f = floorf(fx), y0f = floorf(fy);
        const float wx = fx - x0f, wy = fy - y0f;
        const int x0 = (int)x0f, y0 = (int)y0f;
        const float aV = aws[q][h * 20 + l * 4 + p];
        const bool xin0 = (x0 >= 0) & (x0 < Wl);
        const bool xin1 = (x0 >= -1) & (x0 < Wl - 1);
        const bool yin0 = (y0 >= 0) & (y0 < Wl);
        const bool yin1 = (y0 >= -1) & (y0 < Wl - 1);
        const float w00 = (xin0 & yin0) ? (1.f - wx) * (1.f - wy) * aV : 0.f;
        const float w10 = (xin1 & yin0) ? wx * (1.f - wy) * aV : 0.f;
        const float w01 = (xin0 & yin1) ? (1.f - wx) * wy * aV : 0.f;
        const float w11 = (xin1 & yin1) ? wx * wy * aV : 0.f;
        // any descriptor with >=1 valid corner has vox in [-185, LIN): clamp only
        // touches all-invalid (all-zero-weight) descriptors -> address safety.
        int b0 = (st + y0 * Wl + x0) * 8;       // vox*8 (head-major element units)
        b0 = b0 < -1520 ? -1520 : b0;
        b0 = b0 > LIN * 8 ? LIN * 8 : b0;
        const int b1 = b0 + Wl * 8;             // y+1 row base
        int4 d4;
        d4.x = b0;
        d4.y = b1;
        d4.z = (int)(f2bf_bits(w00) | (f2bf_bits(w10) << 16));
        d4.w = (int)(f2bf_bits(w01) | (f2bf_bits(w11) << 16));
        dsc[s] = d4;
    }
    __syncthreads();

    // ---- phase C: vectorized sampling. wave = query w; lane = h*8 + j.
    // lane owns corner c=j&3 of samples s = 2k + (j>>2), k=0..9; 16B dwordx4 loads.
    {
        const int h = lane >> 3, j = lane & 7;
        const int c = j & 3;                    // corner id (fixed per lane)
        const int sp = j >> 2;                  // sample parity
        const __hip_bfloat16* vbase = valp + (size_t)h * (LIN * 8);
        float acc[8] = {0.f, 0.f, 0.f, 0.f, 0.f, 0.f, 0.f, 0.f};
#pragma unroll
        for (int k = 0; k < 10; k++) {
            const int s = 2 * k + sp;
            const int4 d4 = dsc[(w * 20 + s) * 8 + h];
            const int base = (c >= 2) ? d4.y : d4.x;
            const unsigned wb = (unsigned)((c >= 2) ? d4.w : d4.z);
            const float wt = (c & 1) ? hi16f(wb) : lo16f(wb);
            const short8 v = *(const short8*)(vbase + base + (c & 1) * 8);
#pragma unroll
            for (int d = 0; d < 8; d++)
                acc[d] = fmaf(wt, __uint_as_float(((unsigned)(unsigned short)v[d]) << 16), acc[d]);
        }
        // butterfly reduce across the 8 lanes of this head group
#pragma unroll
        for (int o = 1; o <= 4; o <<= 1)
#pragma unroll
            for (int d = 0; d < 8; d++)
                acc[d] += __shfl_xor(acc[d], o, 64);
        // every lane of the group now holds all 8 channel sums; lane j keeps ch j
        float r = acc[0];
#pragma unroll
        for (int d = 1; d < 8; d++) r = (j == d) ? acc[d] : r;
        qb[w][lane] = __float2bfloat16(r);      // rows 4-15 stay zero
    }
    __syncthreads();

    // ---- phase D: attn @ Wout + bout via MFMA (wave w owns ntile w) ----
    {
        f32x4 acc = {0.f, 0.f, 0.f, 0.f};
#pragma unroll
        for (int kc = 0; kc < 2; kc++) {
            const short8 a = *(const short8*)&qb[m16][kc * 32 + qd * 8];
            const short8 b = *(const short8*)(Woutp + ((size_t)(w * 2 + kc) * 64 + lane) * 8);
            acc = __builtin_amdgcn_mfma_f32_16x16x32_bf16(a, b, acc, 0, 0, 0);
        }
        if (qd == 0) {
            const int n = w * 16 + m16;
            const float bn = bout[n];
#pragma unroll
            for (int r = 0; r < 4; r++) xs4[r][n] = acc[r] + bn;
        }
    }
    __syncthreads();

    // ---- LN1 (wave w = query w); residual qf; store x1 ----
    {
        const float xpre = qf + xs4[w][lane];
        float s = xpre, s2 = xpre * xpre;
#pragma unroll
        for (int o = 32; o >= 1; o >>= 1) {
            s += __shfl_xor(s, o, 64);
            s2 += __shfl_xor(s2, o, 64);
        }
        const float mean = s * (1.f / 64.f);
        const float var = s2 * (1.f / 64.f) - mean * mean;
        const float xn = (xpre - mean) * rsqrtf(var + 1e-5f);
        xout[(size_t)qi * DM + lane] = xn * g1[lane] + b1[lane];
    }
}

// ---- kernel 4: FFN via MFMA, 32 queries/block, hidden in 4 quarters; 29.7 KB LDS ----
__global__ void __launch_bounds__(256)
ffn_kernel(const __hip_bfloat16* __restrict__ W1p, const float* __restrict__ bff1,
           const __hip_bfloat16* __restrict__ W2p, const float* __restrict__ bff2,
           const float* __restrict__ g2, const float* __restrict__ b2,
           float* __restrict__ io) {
    __shared__ __align__(16) __hip_bfloat16 xb[32][72];    // 4608 B
    __shared__ __align__(16) __hip_bfloat16 hb[32][264];   // 16896 B (256 cols + pad)
    __shared__ __align__(16) float yr[32][64];             // 8192 B

    const int tid = threadIdx.x;
    const int lane = tid & 63;
    const int w = tid >> 6;
    const int m16 = lane & 15, qd = lane >> 4;
    const int q0 = blockIdx.x * 32;

    // ---- load x1: thread t -> query t>>3, cols (t&7)*8 .. +7 (bf16 only; f32 reloaded at LN) ----
    {
        const int q = tid >> 3, i = tid & 7;
        const float4 v0 = *(const float4*)&io[(size_t)(q0 + q) * DM + i * 8];
        const float4 v1 = *(const float4*)&io[(size_t)(q0 + q) * DM + i * 8 + 4];
        __hip_bfloat16* xp = &xb[q][i * 8];
        xp[0] = __float2bfloat16(v0.x); xp[1] = __float2bfloat16(v0.y);
        xp[2] = __float2bfloat16(v0.z); xp[3] = __float2bfloat16(v0.w);
        xp[4] = __float2bfloat16(v1.x); xp[5] = __float2bfloat16(v1.y);
        xp[6] = __float2bfloat16(v1.z); xp[7] = __float2bfloat16(v1.w);
    }
    __syncthreads();

    f32x4 yacc[2];
    yacc[0] = (f32x4){0.f, 0.f, 0.f, 0.f};
    yacc[1] = (f32x4){0.f, 0.f, 0.f, 0.f};

#pragma unroll
    for (int qtr = 0; qtr < 4; qtr++) {
        // GEMM1 quarter: hidden cols [qtr*256, +256); wave w does ntiles qtr*16 + w + 4*ti
#pragma unroll
        for (int ti = 0; ti < 4; ti++) {
            const int nt = qtr * 16 + w + ti * 4;
            f32x4 acc[2];
            acc[0] = (f32x4){0.f, 0.f, 0.f, 0.f};
            acc[1] = (f32x4){0.f, 0.f, 0.f, 0.f};
#pragma unroll
            for (int kc = 0; kc < 2; kc++) {
                const short8 b = *(const short8*)(W1p + ((size_t)(nt * 2 + kc) * 64 + lane) * 8);
#pragma unroll
                for (int mt = 0; mt < 2; mt++) {
                    const short8 a = *(const short8*)&xb[mt * 16 + m16][kc * 32 + qd * 8];
                    acc[mt] = __builtin_amdgcn_mfma_f32_16x16x32_bf16(a, b, acc[mt], 0, 0, 0);
                }
            }
            const int ncol = (nt - qtr * 16) * 16 + m16;   // 0..255
            const float bn = bff1[nt * 16 + m16];
#pragma unroll
            for (int mt = 0; mt < 2; mt++)
#pragma unroll
                for (int r = 0; r < 4; r++)
                    hb[mt * 16 + qd * 4 + r][ncol] = __float2bfloat16(fmaxf(acc[mt][r] + bn, 0.f));
        }
        __syncthreads();
        // GEMM2 partial: wave w owns y-ntile w; this quarter's 8 kchunks
#pragma unroll
        for (int kc2 = 0; kc2 < 8; kc2++) {
            const short8 b = *(const short8*)(W2p + ((size_t)(w * 32 + qtr * 8 + kc2) * 64 + lane) * 8);
#pragma unroll
            for (int mt = 0; mt < 2; mt++) {
                const short8 a = *(const short8*)&hb[mt * 16 + m16][kc2 * 32 + qd * 8];
                yacc[mt] = __builtin_amdgcn_mfma_f32_16x16x32_bf16(a, b, yacc[mt], 0, 0, 0);
            }
        }
        __syncthreads();   // hb consumed before next quarter overwrites
    }

    // ---- Y + bff2 (x1 residual re-read from io at LN stage) ----
    {
        const int n = w * 16 + m16;
        const float bn = bff2[n];
#pragma unroll
        for (int mt = 0; mt < 2; mt++)
#pragma unroll
            for (int r = 0; r < 4; r++) {
                const int mm = mt * 16 + qd * 4 + r;
                yr[mm][n] = yacc[mt][r] + bn;
            }
    }
    __syncthreads();

    // ---- LN2 + store: thread t -> query t>>3, cols (t&7)*8..+7; 8-lane reduce ----
    {
        const int q = tid >> 3, i = tid & 7;
        const float4 x0 = *(const float4*)&io[(size_t)(q0 + q) * DM + i * 8];
        const float4 x1 = *(const float4*)&io[(size_t)(q0 + q) * DM + i * 8 + 4];
        float4 v0 = *(const float4*)&yr[q][i * 8];
        float4 v1 = *(const float4*)&yr[q][i * 8 + 4];
        v0.x += x0.x; v0.y += x0.y; v0.z += x0.z; v0.w += x0.w;
        v1.x += x1.x; v1.y += x1.y; v1.z += x1.z; v1.w += x1.w;
        float s = v0.x + v0.y + v0.z + v0.w + v1.x + v1.y + v1.z + v1.w;
        float s2 = v0.x * v0.x + v0.y * v0.y + v0.z * v0.z + v0.w * v0.w
                 + v1.x * v1.x + v1.y * v1.y + v1.z * v1.z + v1.w * v1.w;
#pragma unroll
        for (int o = 4; o >= 1; o >>= 1) { s += __shfl_xor(s, o, 64); s2 += __shfl_xor(s2, o, 64); }
        const float mean = s * (1.f / 64.f);
        const float var = s2 * (1.f / 64.f) - mean * mean;
        const float rstd = rsqrtf(var + 1e-5f);
        const float4 ga = *(const float4*)&g2[i * 8];
        const float4 gb = *(const float4*)&g2[i * 8 + 4];
        const float4 ba4 = *(const float4*)&b2[i * 8];
        const float4 bb4 = *(const float4*)&b2[i * 8 + 4];
        float4 o0, o1;
        o0.x = (v0.x - mean) * rstd * ga.x + ba4.x;
        o0.y = (v0.y - mean) * rstd * ga.y + ba4.y;
        o0.z = (v0.z - mean) * rstd * ga.z + ba4.z;
        o0.w = (v0.w - mean) * rstd * ga.w + ba4.w;
        o1.x = (v1.x - mean) * rstd * gb.x + bb4.x;
        o1.y = (v1.y - mean) * rstd * gb.y + bb4.y;
        o1.z = (v1.z - mean) * rstd * gb.z + bb4.z;
        o1.w = (v1.w - mean) * rstd * gb.w + bb4.w;
        *(float4*)&io[(size_t)(q0 + q) * DM + i * 8] = o0;
        *(float4*)&io[(size_t)(q0 + q) * DM + i * 8 + 4] = o1;
    }
}

extern "C" void kernel_launch(void* const* d_in, const int* in_sizes, int n_in,
                              void* d_out, int out_size, void* d_ws, size_t ws_size,
                              hipStream_t stream) {
    const int B0 = (in_sizes[4] >= 4096) ? 4 : 6;   // int side-inputs present -> 6
    const float* q_feat = (const float*)d_in[0];
    const float* dvf    = (const float*)d_in[1];
    const float* refp   = (const float*)d_in[2];
    const float* q_pos  = (const float*)d_in[3];
    const float* Wv   = (const float*)d_in[B0 + 0];
    const float* bv   = (const float*)d_in[B0 + 1];
    const float* Wo   = (const float*)d_in[B0 + 2];
    const float* bo   = (const float*)d_in[B0 + 3];
    const float* Wa   = (const float*)d_in[B0 + 4];
    const float* ba   = (const float*)d_in[B0 + 5];
    const float* Wout = (const float*)d_in[B0 + 6];
    const float* bout = (const float*)d_in[B0 + 7];
    const float* g1   = (const float*)d_in[B0 + 8];
    const float* b1   = (const float*)d_in[B0 + 9];
    const float* W1   = (const float*)d_in[B0 + 10];
    const float* bff1 = (const float*)d_in[B0 + 11];
    const float* W2   = (const float*)d_in[B0 + 12];
    const float* bff2 = (const float*)d_in[B0 + 13];
    const float* g2   = (const float*)d_in[B0 + 14];
    const float* b2   = (const float*)d_in[B0 + 15];
    float* out = (float*)d_out;

    const size_t val_elems = (size_t)LIN * DM;
    const size_t pack_elems = (size_t)(128 + 128 + 60 + 8) * 64 * 8;   // 165888 bf16
    const size_t PAD_ELEMS = 12288;    // guard pad: derived OOB corners read here x0
    const bool dbuf = ws_size >= (pack_elems + 2 * val_elems + PAD_ELEMS) * sizeof(__hip_bfloat16);

    __hip_bfloat16* W1p = (__hip_bfloat16*)d_ws;
    __hip_bfloat16* W2p = W1p + (size_t)128 * 64 * 8;
    __hip_bfloat16* Woap = W2p + (size_t)128 * 64 * 8;
    __hip_bfloat16* Woutp = Woap + (size_t)60 * 64 * 8;
    __hip_bfloat16* val0 = W1p + pack_elems;
    __hip_bfloat16* val1 = dbuf ? val0 + val_elems : val0;

    // zero the guard pad after the value buffer(s): uninitialized workspace could
    // hold NaN bf16 patterns, and 0-weight x NaN = NaN. (graph-capture-safe)
    __hip_bfloat16* pad_ptr = val1 + val_elems;
    hipMemsetAsync(pad_ptr, 0, PAD_ELEMS * sizeof(__hip_bfloat16), stream);

    pack_kernel<<<81, 256, 0, stream>>>(W1, W2, Wo, Wa, Wout, W1p, W2p, Woap, Woutp);

    if (dbuf) {
        val_proj_kernel<<<(2 * LIN + 63) / 64, 256, 0, stream>>>(
            dvf, Wv, bv, val0, val1, 2 * LIN);
        attn4_kernel<<<(NB * NQ) / 4, 256, 0, stream>>>(
            q_feat, refp, q_pos, Woap, bo, ba, Woutp, bout, g1, b1,
            val0, val1, 0, out);
    } else {
        for (int b = 0; b < NB; b++) {
            val_proj_kernel<<<(LIN + 63) / 64, 256, 0, stream>>>(
                dvf + (size_t)b * val_elems, Wv, bv, val0, val0, LIN);
            attn4_kernel<<<NQ / 4, 256, 0, stream>>>(
                q_feat, refp, q_pos, Woap, bo, ba, Woutp, bout, g1, b1,
                val0, val0, b * NQ, out);
        }
    }
    ffn_kernel<<<(NB * NQ) / 32, 256, 0, stream>>>(W1p, bff1, W2p, bff2, g2, b2, out);
}

// Round 4
// 233.980 us; speedup vs baseline: 1.1342x; 1.0103x over previous
//
#include <hip/hip_runtime.h>
#include <hip/hip_bf16.h>

#define NB 2
#define NQ 20000
#define DM 64
#define NH 8
#define NL 5
#define NP 4
#define LIN 45109
#define FFN 1024

typedef __attribute__((ext_vector_type(8))) short short8;
typedef __attribute__((ext_vector_type(4))) float f32x4;

__device__ __forceinline__ float b2f(const __hip_bfloat16 h) { return __bfloat162float(h); }
__device__ __forceinline__ float lo16f(unsigned u) { return __uint_as_float(u << 16); }
__device__ __forceinline__ float hi16f(unsigned u) { return __uint_as_float(u & 0xffff0000u); }
__device__ __forceinline__ unsigned f2bf_bits(float x) {   // RNE round to bf16 bits
    unsigned u = __float_as_uint(x);
    return (u + 0x7FFFu + ((u >> 16) & 1u)) >> 16;
}

// ---- kernel 1: val = dvf @ Wv + bv via MFMA; head-major output [h][voxel][8] ----
// Swapped-operand MFMA: D = Wv^T * dvf^T -> lane holds 4 CONSECUTIVE CHANNELS of
// one voxel -> packed 8B stores (4/thread) instead of 16 scalar 2B stores.
__global__ void __launch_bounds__(256)
val_proj_kernel(const float* __restrict__ dvf,
                const float* __restrict__ Wv,
                const float* __restrict__ bv,
                __hip_bfloat16* __restrict__ valA,
                __hip_bfloat16* __restrict__ valB,
                int rows) {
    __shared__ __align__(16) __hip_bfloat16 wvp[8][64][8];  // frags: seg = nt*2+kc
    __shared__ __align__(16) __hip_bfloat16 ar[64][72];     // dvf rows
    __shared__ __align__(16) float bvs[64];

    const int tid = threadIdx.x;
    const int lane = tid & 63;
    const int w = tid >> 6;
    const int m16 = lane & 15, qd = lane >> 4;
    const int row0 = blockIdx.x * 64;

    // pack Wv (64x64): lane l, j holds Wv[k=kc*32+(l>>4)*8+j][n=nt*16+(l&15)]
    // (same data serves as A-frag of Wv^T: A[m=n][k])
    for (int idx = tid; idx < 4096; idx += 256) {
        const int j = idx & 7;
        const int l = (idx >> 3) & 63;
        const int seg = idx >> 9;
        const int nt = seg >> 1, kc = seg & 1;
        const int n = nt * 16 + (l & 15);
        const int k = kc * 32 + (l >> 4) * 8 + j;
        wvp[seg][l][j] = __float2bfloat16(Wv[k * 64 + n]);
    }
    if (tid < 64) bvs[tid] = bv[tid];

    // wave w loads its 16 rows: lane -> row w*16+m16, cols qd*16..+15 (4x float4)
    {
        const int r = w * 16 + m16;
        const int grow = row0 + r;
        const int c0 = qd * 16;
        __hip_bfloat16* dst = &ar[r][c0];
        if (grow < rows) {
            const float4* src = (const float4*)&dvf[(size_t)grow * DM + c0];
#pragma unroll
            for (int t = 0; t < 4; t++) {
                const float4 v = src[t];
                dst[t * 4 + 0] = __float2bfloat16(v.x);
                dst[t * 4 + 1] = __float2bfloat16(v.y);
                dst[t * 4 + 2] = __float2bfloat16(v.z);
                dst[t * 4 + 3] = __float2bfloat16(v.w);
            }
        } else {
#pragma unroll
            for (int t = 0; t < 16; t++) dst[t] = __float2bfloat16(0.f);
        }
    }
    __syncthreads();

    // wave w owns voxel n-tile w: D[m=channel][n=voxel], 4 m-tiles x 2 kchunks
    f32x4 acc[4];
#pragma unroll
    for (int mt = 0; mt < 4; mt++) acc[mt] = (f32x4){0.f, 0.f, 0.f, 0.f};
#pragma unroll
    for (int kc = 0; kc < 2; kc++) {
        const short8 b = *(const short8*)&ar[w * 16 + m16][kc * 32 + qd * 8];  // B-frag dvf^T
#pragma unroll
        for (int mt = 0; mt < 4; mt++) {
            const short8 a = *(const short8*)&wvp[mt * 2 + kc][lane][0];       // A-frag Wv^T
            acc[mt] = __builtin_amdgcn_mfma_f32_16x16x32_bf16(a, b, acc[mt], 0, 0, 0);
        }
    }

    // store: lane's voxel = row0 + w*16 + m16; channels mt*16+qd*4 .. +3 (packed 8B)
    {
        const int vg = row0 + w * 16 + m16;
        if (vg < rows) {
            const int vr = (vg < LIN) ? vg : vg - LIN;
            __hip_bfloat16* dst = (vg < LIN) ? valA : valB;
#pragma unroll
            for (int mt = 0; mt < 4; mt++) {
                const int c0 = mt * 16 + qd * 4;
                const float4 bv4 = *(const float4*)&bvs[c0];
                const float r0 = acc[mt][0] + bv4.x, r1 = acc[mt][1] + bv4.y;
                const float r2 = acc[mt][2] + bv4.z, r3 = acc[mt][3] + bv4.w;
                uint2 u;
                u.x = f2bf_bits(r0) | (f2bf_bits(r1) << 16);
                u.y = f2bf_bits(r2) | (f2bf_bits(r3) << 16);
                *(uint2*)&dst[((size_t)(c0 >> 3) * LIN + vr) * 8 + (c0 & 7)] = u;
            }
        }
    }
}

// ---- kernel 2: pack W1/W2/[Wo|Wa]/Wout to bf16 MFMA B-fragment order ----
// B-frag 16x16x32: lane holds B[k=(lane>>4)*8+j][n=lane&15], j=0..7.
__global__ void pack_kernel(const float* __restrict__ W1, const float* __restrict__ W2,
                            const float* __restrict__ Wo, const float* __restrict__ Wa,
                            const float* __restrict__ Wout,
                            __hip_bfloat16* __restrict__ W1p, __hip_bfloat16* __restrict__ W2p,
                            __hip_bfloat16* __restrict__ Woap, __hip_bfloat16* __restrict__ Woutp) {
    const int t = blockIdx.x * 256 + threadIdx.x;
    const int lane = t & 63;
    const int m = lane & 15, qd = lane >> 4;
    const int seg = t >> 6;
    if (seg < 128) {                  // W1 (64x1024): 64 ntiles x 2 kchunks
        const int nt = seg >> 1, kc = seg & 1;
        const int n = nt * 16 + m, kb = kc * 32 + qd * 8;
        __hip_bfloat16* dst = W1p + ((size_t)seg * 64 + lane) * 8;
#pragma unroll
        for (int j = 0; j < 8; j++) dst[j] = __float2bfloat16(W1[(size_t)(kb + j) * FFN + n]);
    } else if (seg < 256) {           // W2 (1024x64): 4 ntiles x 32 kchunks
        const int sl = seg - 128;
        const int nt = sl >> 5, kc = sl & 31;
        const int n = nt * 16 + m, kb = kc * 32 + qd * 8;
        __hip_bfloat16* dst = W2p + ((size_t)sl * 64 + lane) * 8;
#pragma unroll
        for (int j = 0; j < 8; j++) dst[j] = __float2bfloat16(W2[(size_t)(kb + j) * DM + n]);
    } else if (seg < 316) {           // [Wo|Wa] (64x480): 30 ntiles x 2 kchunks
        const int sl = seg - 256;
        const int nt = sl >> 1, kc = sl & 1;
        const int n = nt * 16 + m, kb = kc * 32 + qd * 8;
        __hip_bfloat16* dst = Woap + ((size_t)sl * 64 + lane) * 8;
#pragma unroll
        for (int j = 0; j < 8; j++) {
            const int k = kb + j;
            const float v = (n < 320) ? Wo[(size_t)k * 320 + n] : Wa[(size_t)k * 160 + (n - 320)];
            dst[j] = __float2bfloat16(v);
        }
    } else if (seg < 324) {           // Wout (64x64): 4 ntiles x 2 kchunks (R8-validated)
        const int sl = seg - 316;
        const int nt = sl >> 1, kc = sl & 1;
        const int n = nt * 16 + m, kb = kc * 32 + qd * 8;
        __hip_bfloat16* dst = Woutp + ((size_t)sl * 64 + lane) * 8;
#pragma unroll
        for (int j = 0; j < 8; j++) dst[j] = __float2bfloat16(Wout[(size_t)(kb + j) * DM + n]);
    }
}

// ---- kernel 3: attn, 4 queries/block; value head-major [h][voxel][8] ----
// Phase C vectorized: lane (h,j) loads whole 16B corner segments (dwordx4);
// reduce-scatter butterfly (7 shfl) leaves lane j holding channel j directly.
// LDS 20288B -> 8 blocks/CU. Zero-weight OOB corners read garbage x 0:
// below -> pack region (finite), above -> zeroed guard pad (launch memset).
__global__ void __launch_bounds__(256, 8)
attn4_kernel(const float* __restrict__ q_feat,
             const float* __restrict__ ref_pts,
             const float* __restrict__ q_pos,
             const __hip_bfloat16* __restrict__ Woap,
             const float* __restrict__ bo, const float* __restrict__ ba,
             const __hip_bfloat16* __restrict__ Woutp, const float* __restrict__ bout,
             const float* __restrict__ g1, const float* __restrict__ b1,
             const __hip_bfloat16* __restrict__ valA,
             const __hip_bfloat16* __restrict__ valB,
             int qoff,
             float* __restrict__ xout) {
    __shared__ __align__(16) __hip_bfloat16 qb[16][72];   // A-frag; rows 4-15 zero
    __shared__ __align__(16) float offs[4][321];          // phase-D xs4 aliases this
    __shared__ __align__(16) float aws[4][161];
    __shared__ __align__(16) float refs[4][2];
    __shared__ __align__(16) int4  dsc[640];              // {b0, b1, w01, w23} per (q,s,h)

    float (*xs4)[64] = (float(*)[64])offs;                // offs dead after descriptors

    const int tid = threadIdx.x;
    const int lane = tid & 63;
    const int w = tid >> 6;
    const int m16 = lane & 15, qd = lane >> 4;
    const int q0 = qoff + blockIdx.x * 4;                 // all 4 queries same batch
    const int qi = q0 + w;

    const int sz[NL]  = {184, 92, 46, 23, 12};
    const int lsi[NL] = {0, 33856, 42320, 44436, 44965};

    const __hip_bfloat16* valp = (q0 >= NQ) ? valB : valA;

    // ---- phase A: wave w owns query w ----
    const float qf = q_feat[(size_t)qi * DM + lane];
    const float qp = q_pos[(size_t)qi * DM + lane];
    qb[w][lane] = __float2bfloat16(qf + qp);
    for (int idx = tid; idx < 12 * 16; idx += 256)        // rows 4-15 zero, 8B stores
        *(uint2*)&qb[4 + (idx >> 4)][(idx & 15) * 4] = (uint2){0u, 0u};
    if (tid < 8) refs[tid >> 1][tid & 1] = ref_pts[(size_t)(q0 + (tid >> 1)) * 2 + (tid & 1)];
    __syncthreads();

    // ---- phase B: [offs|aws] = q @ [Wo|Wa] + bias via MFMA (rows 0-3 valid) ----
    for (int nt = w; nt < 30; nt += 4) {
        f32x4 acc = {0.f, 0.f, 0.f, 0.f};
#pragma unroll
        for (int kc = 0; kc < 2; kc++) {
            const short8 a = *(const short8*)&qb[m16][kc * 32 + qd * 8];
            const short8 b = *(const short8*)(Woap + ((size_t)(nt * 2 + kc) * 64 + lane) * 8);
            acc = __builtin_amdgcn_mfma_f32_16x16x32_bf16(a, b, acc, 0, 0, 0);
        }
        if (qd == 0) {                       // rows 0..3 = queries 0..3
            const int n = nt * 16 + m16;
            if (n < 320) {
                const float bn = bo[n];
#pragma unroll
                for (int r = 0; r < 4; r++) offs[r][n] = acc[r] + bn;
            } else {
                const float bn = ba[n - 320];
#pragma unroll
                for (int r = 0; r < 4; r++) aws[r][n - 320] = acc[r] + bn;
            }
        }
    }
    __syncthreads();

    // ---- softmax per (query, head) over 20: 8 lanes per group, all 256 threads ----
    {
        const int g = tid >> 3;               // 0..31 = q*8 + h
        const int q = g >> 3, h = g & 7;
        const int j = tid & 7;
        float* p = &aws[q][h * 20];
        const float v0 = p[j], v1 = p[j + 8];
        const float v2 = (j < 4) ? p[j + 16] : -1e30f;
        float mx = fmaxf(fmaxf(v0, v1), v2);
        mx = fmaxf(mx, __shfl_xor(mx, 1, 8));
        mx = fmaxf(mx, __shfl_xor(mx, 2, 8));
        mx = fmaxf(mx, __shfl_xor(mx, 4, 8));
        const float e0 = __expf(v0 - mx), e1 = __expf(v1 - mx);
        const float e2 = (j < 4) ? __expf(v2 - mx) : 0.f;
        float s = e0 + e1 + e2;
        s += __shfl_xor(s, 1, 8);
        s += __shfl_xor(s, 2, 8);
        s += __shfl_xor(s, 4, 8);
        const float inv = 1.f / s;
        p[j] = e0 * inv;
        p[j + 8] = e1 * inv;
        if (j < 4) p[j + 16] = e2 * inv;
    }
    __syncthreads();

    // ---- precompute sample descriptors: s = ((q*5+l)*4+p)*8 + h ----
    // (ref + o/W)*W - 0.5 == fmaf(ref, W, o) - 0.5  -> no division.
    for (int s = tid; s < 640; s += 256) {
        const int h = s & 7;
        const int t2 = s >> 3;
        const int p = t2 & 3;
        const int t3 = t2 >> 2;           // q*5 + l
        const int l = t3 % 5;
        const int q = t3 / 5;
        const int Wl = sz[l];
        const float Wf = (float)Wl;
        const int st = lsi[l];
        const int c = ((h * 5 + l) * 4 + p) * 2;
        const float fx = fmaf(refs[q][0], Wf, offs[q][c]) - 0.5f;
        const float fy = fmaf(refs[q][1], Wf, offs[q][c + 1]) - 0.5f;
        const float x0f = floorf(fx), y0f = floorf(fy);
        const float wx = fx - x0f, wy = fy - y0f;
        const int x0 = (int)x0f, y0 = (int)y0f;
        const float aV = aws[q][h * 20 + l * 4 + p];
        const bool xin0 = (x0 >= 0) & (x0 < Wl);
        const bool xin1 = (x0 >= -1) & (x0 < Wl - 1);
        const bool yin0 = (y0 >= 0) & (y0 < Wl);
        const bool yin1 = (y0 >= -1) & (y0 < Wl - 1);
        const float w00 = (xin0 & yin0) ? (1.f - wx) * (1.f - wy) * aV : 0.f;
        const float w10 = (xin1 & yin0) ? wx * (1.f - wy) * aV : 0.f;
        const float w01 = (xin0 & yin1) ? (1.f - wx) * wy * aV : 0.f;
        const float w11 = (xin1 & yin1) ? wx * wy * aV : 0.f;
        // any descriptor with >=1 valid corner has vox in [-185, LIN): clamp only
        // touches all-invalid (all-zero-weight) descriptors -> address safety.
        int b0 = (st + y0 * Wl + x0) * 8;       // vox*8 (head-major element units)
        b0 = b0 < -1520 ? -1520 : b0;
        b0 = b0 > LIN * 8 ? LIN * 8 : b0;
        const int b1i = b0 + Wl * 8;            // y+1 row base
        int4 d4;
        d4.x = b0;
        d4.y = b1i;
        d4.z = (int)(f2bf_bits(w00) | (f2bf_bits(w10) << 16));
        d4.w = (int)(f2bf_bits(w01) | (f2bf_bits(w11) << 16));
        dsc[s] = d4;
    }
    __syncthreads();

    // ---- phase C: vectorized sampling. wave = query w; lane = h*8 + j.
    // lane owns corner c=j&3 of samples s = 2k + (j>>2), k=0..9; 16B dwordx4 loads.
    {
        const int h = lane >> 3, j = lane & 7;
        const int c = j & 3;                    // corner id (fixed per lane)
        const int sp = j >> 2;                  // sample parity
        const __hip_bfloat16* vbase = valp + (size_t)h * (LIN * 8);
        float acc[8] = {0.f, 0.f, 0.f, 0.f, 0.f, 0.f, 0.f, 0.f};
#pragma unroll
        for (int k = 0; k < 10; k++) {
            const int s = 2 * k + sp;
            const int4 d4 = dsc[(w * 20 + s) * 8 + h];
            const int base = (c >= 2) ? d4.y : d4.x;
            const unsigned wb = (unsigned)((c >= 2) ? d4.w : d4.z);
            const float wt = (c & 1) ? hi16f(wb) : lo16f(wb);
            const short8 v = *(const short8*)(vbase + base + (c & 1) * 8);
#pragma unroll
            for (int d = 0; d < 8; d++)
                acc[d] = fmaf(wt, __uint_as_float(((unsigned)(unsigned short)v[d]) << 16), acc[d]);
        }
        // reduce-scatter across the 8 lanes of this head group: lane j ends w/ ch j
        const bool hi4 = (j & 4) != 0;
        float k4[4], gv4[4];
#pragma unroll
        for (int d = 0; d < 4; d++) {
            k4[d] = hi4 ? acc[d + 4] : acc[d];
            gv4[d] = hi4 ? acc[d] : acc[d + 4];
        }
#pragma unroll
        for (int d = 0; d < 4; d++) k4[d] += __shfl_xor(gv4[d], 4, 64);
        const bool hi2 = (j & 2) != 0;
        float k2[2], gv2[2];
#pragma unroll
        for (int d = 0; d < 2; d++) {
            k2[d] = hi2 ? k4[d + 2] : k4[d];
            gv2[d] = hi2 ? k4[d] : k4[d + 2];
        }
#pragma unroll
        for (int d = 0; d < 2; d++) k2[d] += __shfl_xor(gv2[d], 2, 64);
        const bool hi1 = (j & 1) != 0;
        float k1 = hi1 ? k2[1] : k2[0];
        float gv1 = hi1 ? k2[0] : k2[1];
        k1 += __shfl_xor(gv1, 1, 64);
        qb[w][lane] = __float2bfloat16(k1);     // rows 4-15 stay zero
    }
    __syncthreads();

    // ---- phase D: attn @ Wout + bout via MFMA (wave w owns ntile w) ----
    {
        f32x4 acc = {0.f, 0.f, 0.f, 0.f};
#pragma unroll
        for (int kc = 0; kc < 2; kc++) {
            const short8 a = *(const short8*)&qb[m16][kc * 32 + qd * 8];
            const short8 b = *(const short8*)(Woutp + ((size_t)(w * 2 + kc) * 64 + lane) * 8);
            acc = __builtin_amdgcn_mfma_f32_16x16x32_bf16(a, b, acc, 0, 0, 0);
        }
        if (qd == 0) {
            const int n = w * 16 + m16;
            const float bn = bout[n];
#pragma unroll
            for (int r = 0; r < 4; r++) xs4[r][n] = acc[r] + bn;
        }
    }
    __syncthreads();

    // ---- LN1 (wave w = query w); residual qf; store x1 ----
    {
        const float xpre = qf + xs4[w][lane];
        float s = xpre, s2 = xpre * xpre;
#pragma unroll
        for (int o = 32; o >= 1; o >>= 1) {
            s += __shfl_xor(s, o, 64);
            s2 += __shfl_xor(s2, o, 64);
        }
        const float mean = s * (1.f / 64.f);
        const float var = s2 * (1.f / 64.f) - mean * mean;
        const float xn = (xpre - mean) * rsqrtf(var + 1e-5f);
        xout[(size_t)qi * DM + lane] = xn * g1[lane] + b1[lane];
    }
}

// ---- kernel 4: FFN via MFMA, 32 queries/block, hidden in 4 quarters ----
// GEMM1 swapped: D = W1^T * x^T -> lane holds 4 consecutive hidden values of one
// query -> packed ds_write_b64 into hb[query][hidden] (GEMM2 A-reads unchanged).
// x staged once in B-frag layout (4 ds_read_b128 total). ~28.6 KB LDS.
__global__ void __launch_bounds__(256)
ffn_kernel(const __hip_bfloat16* __restrict__ W1p, const float* __restrict__ bff1,
           const __hip_bfloat16* __restrict__ W2p, const float* __restrict__ bff2,
           const float* __restrict__ g2, const float* __restrict__ b2,
           float* __restrict__ io) {
    __shared__ __align__(16) __hip_bfloat16 xq[2][2][64][8];  // x B-frags: [ntile][kc]
    __shared__ __align__(16) __hip_bfloat16 hb[32][264];      // 16896 B (256 cols + pad)
    __shared__ __align__(16) float yr[32][64];                // 8192 B

    const int tid = threadIdx.x;
    const int lane = tid & 63;
    const int w = tid >> 6;
    const int m16 = lane & 15, qd = lane >> 4;
    const int q0 = blockIdx.x * 32;

    // ---- load x1 -> B-frag layout: thread t -> query t>>3, model dims (t&7)*8..+7
    // dest: xq[q>>4][i>>2][ (q&15) + (i&3)*16 ][0..7]  (16B contiguous)
    {
        const int q = tid >> 3, i = tid & 7;
        const float4 v0 = *(const float4*)&io[(size_t)(q0 + q) * DM + i * 8];
        const float4 v1 = *(const float4*)&io[(size_t)(q0 + q) * DM + i * 8 + 4];
        uint2 ua, ub;
        ua.x = f2bf_bits(v0.x) | (f2bf_bits(v0.y) << 16);
        ua.y = f2bf_bits(v0.z) | (f2bf_bits(v0.w) << 16);
        ub.x = f2bf_bits(v1.x) | (f2bf_bits(v1.y) << 16);
        ub.y = f2bf_bits(v1.z) | (f2bf_bits(v1.w) << 16);
        uint4 u4 = {ua.x, ua.y, ub.x, ub.y};
        *(uint4*)&xq[q >> 4][i >> 2][(q & 15) + (i & 3) * 16][0] = u4;
    }
    __syncthreads();

    // x B-frags: loop-invariant, load once (4 ds_read_b128)
    short8 bx[2][2];
#pragma unroll
    for (int nt = 0; nt < 2; nt++)
#pragma unroll
        for (int kc = 0; kc < 2; kc++)
            bx[nt][kc] = *(const short8*)&xq[nt][kc][lane][0];

    f32x4 yacc[2];
    yacc[0] = (f32x4){0.f, 0.f, 0.f, 0.f};
    yacc[1] = (f32x4){0.f, 0.f, 0.f, 0.f};

#pragma unroll
    for (int qtr = 0; qtr < 4; qtr++) {
        // GEMM1 quarter (swapped): hidden m-tiles; wave w does htl = mt*4 + w
#pragma unroll
        for (int mt = 0; mt < 4; mt++) {
            const int htl = mt * 4 + w;            // 0..15 within quarter
            const int ht = qtr * 16 + htl;         // global hidden tile
            f32x4 acc[2];
            acc[0] = (f32x4){0.f, 0.f, 0.f, 0.f};
            acc[1] = (f32x4){0.f, 0.f, 0.f, 0.f};
#pragma unroll
            for (int kc = 0; kc < 2; kc++) {
                const short8 a = *(const short8*)(W1p + ((size_t)(ht * 2 + kc) * 64 + lane) * 8);
#pragma unroll
                for (int nt = 0; nt < 2; nt++)
                    acc[nt] = __builtin_amdgcn_mfma_f32_16x16x32_bf16(a, bx[nt][kc], acc[nt], 0, 0, 0);
            }
            const float4 b4 = *(const float4*)&bff1[ht * 16 + qd * 4];
#pragma unroll
            for (int nt = 0; nt < 2; nt++) {
                const float r0 = fmaxf(acc[nt][0] + b4.x, 0.f);
                const float r1 = fmaxf(acc[nt][1] + b4.y, 0.f);
                const float r2 = fmaxf(acc[nt][2] + b4.z, 0.f);
                const float r3 = fmaxf(acc[nt][3] + b4.w, 0.f);
                uint2 u;
                u.x = f2bf_bits(r0) | (f2bf_bits(r1) << 16);
                u.y = f2bf_bits(r2) | (f2bf_bits(r3) << 16);
                *(uint2*)&hb[nt * 16 + m16][htl * 16 + qd * 4] = u;
            }
        }
        __syncthreads();
        // GEMM2 partial: wave w owns y-ntile w; this quarter's 8 kchunks
#pragma unroll
        for (int kc2 = 0; kc2 < 8; kc2++) {
            const short8 b = *(const short8*)(W2p + ((size_t)(w * 32 + qtr * 8 + kc2) * 64 + lane) * 8);
#pragma unroll
            for (int mt = 0; mt < 2; mt++) {
                const short8 a = *(const short8*)&hb[mt * 16 + m16][kc2 * 32 + qd * 8];
                yacc[mt] = __builtin_amdgcn_mfma_f32_16x16x32_bf16(a, b, yacc[mt], 0, 0, 0);
            }
        }
        __syncthreads();   // hb consumed before next quarter overwrites
    }

    // ---- Y + bff2 (x1 residual re-read from io at LN stage) ----
    {
        const int n = w * 16 + m16;
        const float bn = bff2[n];
#pragma unroll
        for (int mt = 0; mt < 2; mt++)
#pragma unroll
            for (int r = 0; r < 4; r++) {
                const int mm = mt * 16 + qd * 4 + r;
                yr[mm][n] = yacc[mt][r] + bn;
            }
    }
    __syncthreads();

    // ---- LN2 + store: thread t -> query t>>3, cols (t&7)*8..+7; 8-lane reduce ----
    {
        const int q = tid >> 3, i = tid & 7;
        const float4 x0 = *(const float4*)&io[(size_t)(q0 + q) * DM + i * 8];
        const float4 x1 = *(const float4*)&io[(size_t)(q0 + q) * DM + i * 8 + 4];
        float4 v0 = *(const float4*)&yr[q][i * 8];
        float4 v1 = *(const float4*)&yr[q][i * 8 + 4];
        v0.x += x0.x; v0.y += x0.y; v0.z += x0.z; v0.w += x0.w;
        v1.x += x1.x; v1.y += x1.y; v1.z += x1.z; v1.w += x1.w;
        float s = v0.x + v0.y + v0.z + v0.w + v1.x + v1.y + v1.z + v1.w;
        float s2 = v0.x * v0.x + v0.y * v0.y + v0.z * v0.z + v0.w * v0.w
                 + v1.x * v1.x + v1.y * v1.y + v1.z * v1.z + v1.w * v1.w;
#pragma unroll
        for (int o = 4; o >= 1; o >>= 1) { s += __shfl_xor(s, o, 64); s2 += __shfl_xor(s2, o, 64); }
        const float mean = s * (1.f / 64.f);
        const float var = s2 * (1.f / 64.f) - mean * mean;
        const float rstd = rsqrtf(var + 1e-5f);
        const float4 ga = *(const float4*)&g2[i * 8];
        const float4 gb = *(const float4*)&g2[i * 8 + 4];
        const float4 ba4 = *(const float4*)&b2[i * 8];
        const float4 bb4 = *(const float4*)&b2[i * 8 + 4];
        float4 o0, o1;
        o0.x = (v0.x - mean) * rstd * ga.x + ba4.x;
        o0.y = (v0.y - mean) * rstd * ga.y + ba4.y;
        o0.z = (v0.z - mean) * rstd * ga.z + ba4.z;
        o0.w = (v0.w - mean) * rstd * ga.w + ba4.w;
        o1.x = (v1.x - mean) * rstd * gb.x + bb4.x;
        o1.y = (v1.y - mean) * rstd * gb.y + bb4.y;
        o1.z = (v1.z - mean) * rstd * gb.z + bb4.z;
        o1.w = (v1.w - mean) * rstd * gb.w + bb4.w;
        *(float4*)&io[(size_t)(q0 + q) * DM + i * 8] = o0;
        *(float4*)&io[(size_t)(q0 + q) * DM + i * 8 + 4] = o1;
    }
}

extern "C" void kernel_launch(void* const* d_in, const int* in_sizes, int n_in,
                              void* d_out, int out_size, void* d_ws, size_t ws_size,
                              hipStream_t stream) {
    const int B0 = (in_sizes[4] >= 4096) ? 4 : 6;   // int side-inputs present -> 6
    const float* q_feat = (const float*)d_in[0];
    const float* dvf    = (const float*)d_in[1];
    const float* refp   = (const float*)d_in[2];
    const float* q_pos  = (const float*)d_in[3];
    const float* Wv   = (const float*)d_in[B0 + 0];
    const float* bv   = (const float*)d_in[B0 + 1];
    const float* Wo   = (const float*)d_in[B0 + 2];
    const float* bo   = (const float*)d_in[B0 + 3];
    const float* Wa   = (const float*)d_in[B0 + 4];
    const float* ba   = (const float*)d_in[B0 + 5];
    const float* Wout = (const float*)d_in[B0 + 6];
    const float* bout = (const float*)d_in[B0 + 7];
    const float* g1   = (const float*)d_in[B0 + 8];
    const float* b1   = (const float*)d_in[B0 + 9];
    const float* W1   = (const float*)d_in[B0 + 10];
    const float* bff1 = (const float*)d_in[B0 + 11];
    const float* W2   = (const float*)d_in[B0 + 12];
    const float* bff2 = (const float*)d_in[B0 + 13];
    const float* g2   = (const float*)d_in[B0 + 14];
    const float* b2   = (const float*)d_in[B0 + 15];
    float* out = (float*)d_out;

    const size_t val_elems = (size_t)LIN * DM;
    const size_t pack_elems = (size_t)(128 + 128 + 60 + 8) * 64 * 8;   // 165888 bf16
    const size_t PAD_ELEMS = 12288;    // guard pad: derived OOB corners read here x0
    const bool dbuf = ws_size >= (pack_elems + 2 * val_elems + PAD_ELEMS) * sizeof(__hip_bfloat16);

    __hip_bfloat16* W1p = (__hip_bfloat16*)d_ws;
    __hip_bfloat16* W2p = W1p + (size_t)128 * 64 * 8;
    __hip_bfloat16* Woap = W2p + (size_t)128 * 64 * 8;
    __hip_bfloat16* Woutp = Woap + (size_t)60 * 64 * 8;
    __hip_bfloat16* val0 = W1p + pack_elems;
    __hip_bfloat16* val1 = dbuf ? val0 + val_elems : val0;

    // zero the guard pad after the value buffer(s): uninitialized workspace could
    // hold NaN bf16 patterns, and 0-weight x NaN = NaN. (graph-capture-safe)
    __hip_bfloat16* pad_ptr = val1 + val_elems;
    hipMemsetAsync(pad_ptr, 0, PAD_ELEMS * sizeof(__hip_bfloat16), stream);

    pack_kernel<<<81, 256, 0, stream>>>(W1, W2, Wo, Wa, Wout, W1p, W2p, Woap, Woutp);

    if (dbuf) {
        val_proj_kernel<<<(2 * LIN + 63) / 64, 256, 0, stream>>>(
            dvf, Wv, bv, val0, val1, 2 * LIN);
        attn4_kernel<<<(NB * NQ) / 4, 256, 0, stream>>>(
            q_feat, refp, q_pos, Woap, bo, ba, Woutp, bout, g1, b1,
            val0, val1, 0, out);
    } else {
        for (int b = 0; b < NB; b++) {
            val_proj_kernel<<<(LIN + 63) / 64, 256, 0, stream>>>(
                dvf + (size_t)b * val_elems, Wv, bv, val0, val0, LIN);
            attn4_kernel<<<NQ / 4, 256, 0, stream>>>(
                q_feat, refp, q_pos, Woap, bo, ba, Woutp, bout, g1, b1,
                val0, val0, b * NQ, out);
        }
    }
    ffn_kernel<<<(NB * NQ) / 32, 256, 0, stream>>>(W1p, bff1, W2p, bff2, g2, b2, out);
}

// Round 5
// 225.148 us; speedup vs baseline: 1.1787x; 1.0392x over previous
//
#include <hip/hip_runtime.h>
#include <hip/hip_bf16.h>

#define NB 2
#define NQ 20000
#define DM 64
#define NH 8
#define NL 5
#define NP 4
#define LIN 45109
#define FFN 1024

typedef __attribute__((ext_vector_type(8))) short short8;
typedef __attribute__((ext_vector_type(4))) float f32x4;

__device__ __forceinline__ float b2f(const __hip_bfloat16 h) { return __bfloat162float(h); }
__device__ __forceinline__ float lo16f(unsigned u) { return __uint_as_float(u << 16); }
__device__ __forceinline__ float hi16f(unsigned u) { return __uint_as_float(u & 0xffff0000u); }
__device__ __forceinline__ unsigned f2bf_bits(float x) {   // RNE round to bf16 bits
    unsigned u = __float_as_uint(x);
    return (u + 0x7FFFu + ((u >> 16) & 1u)) >> 16;
}

// ---- kernel 1 (fused prep): blocks 0..80 = weight pack, block 81 = guard-pad
// zero, blocks 82.. = val projection (head-major [h][voxel][8] output).
// Replaces pack_kernel + hipMemsetAsync + val_proj_kernel (5 -> 3 dispatches).
__global__ void __launch_bounds__(256)
prep_kernel(const float* __restrict__ dvf,
            const float* __restrict__ Wv, const float* __restrict__ bv,
            const float* __restrict__ W1, const float* __restrict__ W2,
            const float* __restrict__ Wo, const float* __restrict__ Wa,
            const float* __restrict__ Wout,
            __hip_bfloat16* __restrict__ W1p, __hip_bfloat16* __restrict__ W2p,
            __hip_bfloat16* __restrict__ Woap, __hip_bfloat16* __restrict__ Woutp,
            __hip_bfloat16* __restrict__ valA, __hip_bfloat16* __restrict__ valB,
            __hip_bfloat16* __restrict__ pad_ptr,
            int rows) {
    __shared__ __align__(16) __hip_bfloat16 wvp[8][64][8];  // frags: seg = nt*2+kc
    __shared__ __align__(16) __hip_bfloat16 ar[64][72];     // dvf rows
    __shared__ __align__(16) float bvs[64];

    const int tid = threadIdx.x;
    const int bid = blockIdx.x;
    const int lane = tid & 63;
    const int w = tid >> 6;
    const int m16 = lane & 15, qd = lane >> 4;

    if (bid < 81) {
        // ---- weight pack: B-frag 16x16x32: lane holds B[k=(lane>>4)*8+j][n=lane&15]
        const int t = bid * 256 + tid;
        const int m = m16;
        const int seg = t >> 6;
        if (seg < 128) {                  // W1 (64x1024): 64 ntiles x 2 kchunks
            const int nt = seg >> 1, kc = seg & 1;
            const int n = nt * 16 + m, kb = kc * 32 + qd * 8;
            __hip_bfloat16* dst = W1p + ((size_t)seg * 64 + lane) * 8;
#pragma unroll
            for (int j = 0; j < 8; j++) dst[j] = __float2bfloat16(W1[(size_t)(kb + j) * FFN + n]);
        } else if (seg < 256) {           // W2 (1024x64): 4 ntiles x 32 kchunks
            const int sl = seg - 128;
            const int nt = sl >> 5, kc = sl & 31;
            const int n = nt * 16 + m, kb = kc * 32 + qd * 8;
            __hip_bfloat16* dst = W2p + ((size_t)sl * 64 + lane) * 8;
#pragma unroll
            for (int j = 0; j < 8; j++) dst[j] = __float2bfloat16(W2[(size_t)(kb + j) * DM + n]);
        } else if (seg < 316) {           // [Wo|Wa] (64x480): 30 ntiles x 2 kchunks
            const int sl = seg - 256;
            const int nt = sl >> 1, kc = sl & 1;
            const int n = nt * 16 + m, kb = kc * 32 + qd * 8;
            __hip_bfloat16* dst = Woap + ((size_t)sl * 64 + lane) * 8;
#pragma unroll
            for (int j = 0; j < 8; j++) {
                const int k = kb + j;
                const float v = (n < 320) ? Wo[(size_t)k * 320 + n] : Wa[(size_t)k * 160 + (n - 320)];
                dst[j] = __float2bfloat16(v);
            }
        } else if (seg < 324) {           // Wout (64x64): 4 ntiles x 2 kchunks
            const int sl = seg - 316;
            const int nt = sl >> 1, kc = sl & 1;
            const int n = nt * 16 + m, kb = kc * 32 + qd * 8;
            __hip_bfloat16* dst = Woutp + ((size_t)sl * 64 + lane) * 8;
#pragma unroll
            for (int j = 0; j < 8; j++) dst[j] = __float2bfloat16(Wout[(size_t)(kb + j) * DM + n]);
        }
        return;
    }
    if (bid == 81) {
        // ---- zero the guard pad (12288 bf16 = 1536 x 16B); uninit ws may hold NaN
        uint4* p = (uint4*)pad_ptr;
        for (int i = tid; i < 1536; i += 256) p[i] = (uint4){0u, 0u, 0u, 0u};
        return;
    }

    // ---- val projection: swapped-operand MFMA D = Wv^T * dvf^T -> lane holds
    // 4 consecutive channels of one voxel -> packed 8B stores.
    const int row0 = (bid - 82) * 64;

    for (int idx = tid; idx < 4096; idx += 256) {
        const int j = idx & 7;
        const int l = (idx >> 3) & 63;
        const int seg = idx >> 9;
        const int nt = seg >> 1, kc = seg & 1;
        const int n = nt * 16 + (l & 15);
        const int k = kc * 32 + (l >> 4) * 8 + j;
        wvp[seg][l][j] = __float2bfloat16(Wv[k * 64 + n]);
    }
    if (tid < 64) bvs[tid] = bv[tid];

    {
        const int r = w * 16 + m16;
        const int grow = row0 + r;
        const int c0 = qd * 16;
        __hip_bfloat16* dst = &ar[r][c0];
        if (grow < rows) {
            const float4* src = (const float4*)&dvf[(size_t)grow * DM + c0];
#pragma unroll
            for (int t = 0; t < 4; t++) {
                const float4 v = src[t];
                dst[t * 4 + 0] = __float2bfloat16(v.x);
                dst[t * 4 + 1] = __float2bfloat16(v.y);
                dst[t * 4 + 2] = __float2bfloat16(v.z);
                dst[t * 4 + 3] = __float2bfloat16(v.w);
            }
        } else {
#pragma unroll
            for (int t = 0; t < 16; t++) dst[t] = __float2bfloat16(0.f);
        }
    }
    __syncthreads();

    f32x4 acc[4];
#pragma unroll
    for (int mt = 0; mt < 4; mt++) acc[mt] = (f32x4){0.f, 0.f, 0.f, 0.f};
#pragma unroll
    for (int kc = 0; kc < 2; kc++) {
        const short8 b = *(const short8*)&ar[w * 16 + m16][kc * 32 + qd * 8];  // B-frag dvf^T
#pragma unroll
        for (int mt = 0; mt < 4; mt++) {
            const short8 a = *(const short8*)&wvp[mt * 2 + kc][lane][0];       // A-frag Wv^T
            acc[mt] = __builtin_amdgcn_mfma_f32_16x16x32_bf16(a, b, acc[mt], 0, 0, 0);
        }
    }

    {
        const int vg = row0 + w * 16 + m16;
        if (vg < rows) {
            const int vr = (vg < LIN) ? vg : vg - LIN;
            __hip_bfloat16* dst = (vg < LIN) ? valA : valB;
#pragma unroll
            for (int mt = 0; mt < 4; mt++) {
                const int c0 = mt * 16 + qd * 4;
                const float4 bv4 = *(const float4*)&bvs[c0];
                const float r0 = acc[mt][0] + bv4.x, r1 = acc[mt][1] + bv4.y;
                const float r2 = acc[mt][2] + bv4.z, r3 = acc[mt][3] + bv4.w;
                uint2 u;
                u.x = f2bf_bits(r0) | (f2bf_bits(r1) << 16);
                u.y = f2bf_bits(r2) | (f2bf_bits(r3) << 16);
                *(uint2*)&dst[((size_t)(c0 >> 3) * LIN + vr) * 8 + (c0 & 7)] = u;
            }
        }
    }
}

// ---- kernel 3: attn, 4 queries/block; value head-major [h][voxel][8] ----
// Phase C: 2 batches of 5 statically-indexed register loads (dwordx4) -> ~5
// gathers in flight (vs serialized at VGPR=32); reduce-scatter leaves lane j
// with channel j. Phase B: static 8-iter unroll, hoisted A-frags -> clustered
// L2 loads. LDS 20288B -> 8 blocks/CU (32 waves = HW max). Zero-weight OOB
// corners read garbage x 0: below -> pack region (finite), above -> guard pad.
__global__ void __launch_bounds__(256, 8)
attn4_kernel(const float* __restrict__ q_feat,
             const float* __restrict__ ref_pts,
             const float* __restrict__ q_pos,
             const __hip_bfloat16* __restrict__ Woap,
             const float* __restrict__ bo, const float* __restrict__ ba,
             const __hip_bfloat16* __restrict__ Woutp, const float* __restrict__ bout,
             const float* __restrict__ g1, const float* __restrict__ b1,
             const __hip_bfloat16* __restrict__ valA,
             const __hip_bfloat16* __restrict__ valB,
             int qoff,
             float* __restrict__ xout) {
    __shared__ __align__(16) __hip_bfloat16 qb[16][72];   // A-frag; rows 4-15 zero
    __shared__ __align__(16) float offs[4][321];          // phase-D xs4 aliases this
    __shared__ __align__(16) float aws[4][161];
    __shared__ __align__(16) float refs[4][2];
    __shared__ __align__(16) int4  dsc[640];              // {b0, b1, w01, w23} per (q,s,h)

    float (*xs4)[64] = (float(*)[64])offs;                // offs dead after descriptors

    const int tid = threadIdx.x;
    const int lane = tid & 63;
    const int w = tid >> 6;
    const int m16 = lane & 15, qd = lane >> 4;
    const int q0 = qoff + blockIdx.x * 4;                 // all 4 queries same batch
    const int qi = q0 + w;

    const int sz[NL]  = {184, 92, 46, 23, 12};
    const int lsi[NL] = {0, 33856, 42320, 44436, 44965};

    const __hip_bfloat16* valp = (q0 >= NQ) ? valB : valA;

    // ---- phase A: wave w owns query w ----
    const float qf = q_feat[(size_t)qi * DM + lane];
    const float qp = q_pos[(size_t)qi * DM + lane];
    qb[w][lane] = __float2bfloat16(qf + qp);
    for (int idx = tid; idx < 12 * 16; idx += 256)        // rows 4-15 zero, 8B stores
        *(uint2*)&qb[4 + (idx >> 4)][(idx & 15) * 4] = (uint2){0u, 0u};
    if (tid < 8) refs[tid >> 1][tid & 1] = ref_pts[(size_t)(q0 + (tid >> 1)) * 2 + (tid & 1)];
    __syncthreads();

    // ---- phase B: [offs|aws] = q @ [Wo|Wa] + bias via MFMA (rows 0-3 valid) ----
    {
        const short8 qa0 = *(const short8*)&qb[m16][qd * 8];
        const short8 qa1 = *(const short8*)&qb[m16][32 + qd * 8];
#pragma unroll
        for (int t = 0; t < 8; t++) {
            const int nt = w + t * 4;
            if (nt < 30) {
                const short8 b0 = *(const short8*)(Woap + ((size_t)(nt * 2 + 0) * 64 + lane) * 8);
                const short8 b1 = *(const short8*)(Woap + ((size_t)(nt * 2 + 1) * 64 + lane) * 8);
                f32x4 acc = {0.f, 0.f, 0.f, 0.f};
                acc = __builtin_amdgcn_mfma_f32_16x16x32_bf16(qa0, b0, acc, 0, 0, 0);
                acc = __builtin_amdgcn_mfma_f32_16x16x32_bf16(qa1, b1, acc, 0, 0, 0);
                if (qd == 0) {                       // rows 0..3 = queries 0..3
                    const int n = nt * 16 + m16;
                    if (n < 320) {
                        const float bn = bo[n];
#pragma unroll
                        for (int r = 0; r < 4; r++) offs[r][n] = acc[r] + bn;
                    } else {
                        const float bn = ba[n - 320];
#pragma unroll
                        for (int r = 0; r < 4; r++) aws[r][n - 320] = acc[r] + bn;
                    }
                }
            }
        }
    }
    __syncthreads();

    // ---- softmax per (query, head) over 20: 8 lanes per group, all 256 threads ----
    {
        const int g = tid >> 3;               // 0..31 = q*8 + h
        const int q = g >> 3, h = g & 7;
        const int j = tid & 7;
        float* p = &aws[q][h * 20];
        const float v0 = p[j], v1 = p[j + 8];
        const float v2 = (j < 4) ? p[j + 16] : -1e30f;
        float mx = fmaxf(fmaxf(v0, v1), v2);
        mx = fmaxf(mx, __shfl_xor(mx, 1, 8));
        mx = fmaxf(mx, __shfl_xor(mx, 2, 8));
        mx = fmaxf(mx, __shfl_xor(mx, 4, 8));
        const float e0 = __expf(v0 - mx), e1 = __expf(v1 - mx);
        const float e2 = (j < 4) ? __expf(v2 - mx) : 0.f;
        float s = e0 + e1 + e2;
        s += __shfl_xor(s, 1, 8);
        s += __shfl_xor(s, 2, 8);
        s += __shfl_xor(s, 4, 8);
        const float inv = 1.f / s;
        p[j] = e0 * inv;
        p[j + 8] = e1 * inv;
        if (j < 4) p[j + 16] = e2 * inv;
    }
    __syncthreads();

    // ---- precompute sample descriptors: s = ((q*5+l)*4+p)*8 + h ----
    // (ref + o/W)*W - 0.5 == fmaf(ref, W, o) - 0.5  -> no division.
    for (int s = tid; s < 640; s += 256) {
        const int h = s & 7;
        const int t2 = s >> 3;
        const int p = t2 & 3;
        const int t3 = t2 >> 2;           // q*5 + l
        const int l = t3 % 5;
        const int q = t3 / 5;
        const int Wl = sz[l];
        const float Wf = (float)Wl;
        const int st = lsi[l];
        const int c = ((h * 5 + l) * 4 + p) * 2;
        const float fx = fmaf(refs[q][0], Wf, offs[q][c]) - 0.5f;
        const float fy = fmaf(refs[q][1], Wf, offs[q][c + 1]) - 0.5f;
        const float x0f = floorf(fx), y0f = floorf(fy);
        const float wx = fx - x0f, wy = fy - y0f;
        const int x0 = (int)x0f, y0 = (int)y0f;
        const float aV = aws[q][h * 20 + l * 4 + p];
        const bool xin0 = (x0 >= 0) & (x0 < Wl);
        const bool xin1 = (x0 >= -1) & (x0 < Wl - 1);
        const bool yin0 = (y0 >= 0) & (y0 < Wl);
        const bool yin1 = (y0 >= -1) & (y0 < Wl - 1);
        const float w00 = (xin0 & yin0) ? (1.f - wx) * (1.f - wy) * aV : 0.f;
        const float w10 = (xin1 & yin0) ? wx * (1.f - wy) * aV : 0.f;
        const float w01 = (xin0 & yin1) ? (1.f - wx) * wy * aV : 0.f;
        const float w11 = (xin1 & yin1) ? wx * wy * aV : 0.f;
        // any descriptor with >=1 valid corner has vox in [-185, LIN): clamp only
        // touches all-invalid (all-zero-weight) descriptors -> address safety.
        int b0 = (st + y0 * Wl + x0) * 8;       // vox*8 (head-major element units)
        b0 = b0 < -1520 ? -1520 : b0;
        b0 = b0 > LIN * 8 ? LIN * 8 : b0;
        const int b1i = b0 + Wl * 8;            // y+1 row base
        int4 d4;
        d4.x = b0;
        d4.y = b1i;
        d4.z = (int)(f2bf_bits(w00) | (f2bf_bits(w10) << 16));
        d4.w = (int)(f2bf_bits(w01) | (f2bf_bits(w11) << 16));
        dsc[s] = d4;
    }
    __syncthreads();

    // ---- phase C: vectorized sampling. wave = query w; lane = h*8 + j.
    // lane owns corner c=j&3 of samples s = 2k + (j>>2); 2 batches of 5 loads
    // held in statically-indexed register arrays -> MLP (5 gathers in flight).
    {
        const int h = lane >> 3, j = lane & 7;
        const int c = j & 3;                    // corner id (fixed per lane)
        const int sp = j >> 2;                  // sample parity
        const __hip_bfloat16* vbase = valp + (size_t)h * (LIN * 8) + (c & 1) * 8;
        float acc[8] = {0.f, 0.f, 0.f, 0.f, 0.f, 0.f, 0.f, 0.f};
#pragma unroll
        for (int g = 0; g < 2; g++) {
            short8 v[5];
            unsigned wb[5];
#pragma unroll
            for (int k = 0; k < 5; k++) {
                const int s = 2 * (g * 5 + k) + sp;
                const int4 d4 = dsc[(w * 20 + s) * 8 + h];
                const int base = (c >= 2) ? d4.y : d4.x;
                wb[k] = (unsigned)((c >= 2) ? d4.w : d4.z);
                v[k] = *(const short8*)(vbase + base);
            }
#pragma unroll
            for (int k = 0; k < 5; k++) {
                const float wt = (c & 1) ? hi16f(wb[k]) : lo16f(wb[k]);
#pragma unroll
                for (int d = 0; d < 8; d++)
                    acc[d] = fmaf(wt, __uint_as_float(((unsigned)(unsigned short)v[k][d]) << 16), acc[d]);
            }
        }
        // reduce-scatter across the 8 lanes of this head group: lane j ends w/ ch j
        const bool hi4 = (j & 4) != 0;
        float k4[4], gv4[4];
#pragma unroll
        for (int d = 0; d < 4; d++) {
            k4[d] = hi4 ? acc[d + 4] : acc[d];
            gv4[d] = hi4 ? acc[d] : acc[d + 4];
        }
#pragma unroll
        for (int d = 0; d < 4; d++) k4[d] += __shfl_xor(gv4[d], 4, 64);
        const bool hi2 = (j & 2) != 0;
        float k2[2], gv2[2];
#pragma unroll
        for (int d = 0; d < 2; d++) {
            k2[d] = hi2 ? k4[d + 2] : k4[d];
            gv2[d] = hi2 ? k4[d] : k4[d + 2];
        }
#pragma unroll
        for (int d = 0; d < 2; d++) k2[d] += __shfl_xor(gv2[d], 2, 64);
        const bool hi1 = (j & 1) != 0;
        float k1 = hi1 ? k2[1] : k2[0];
        float gv1 = hi1 ? k2[0] : k2[1];
        k1 += __shfl_xor(gv1, 1, 64);
        qb[w][lane] = __float2bfloat16(k1);     // rows 4-15 stay zero
    }
    __syncthreads();

    // ---- phase D: attn @ Wout + bout via MFMA (wave w owns ntile w) ----
    {
        f32x4 acc = {0.f, 0.f, 0.f, 0.f};
#pragma unroll
        for (int kc = 0; kc < 2; kc++) {
            const short8 a = *(const short8*)&qb[m16][kc * 32 + qd * 8];
            const short8 b = *(const short8*)(Woutp + ((size_t)(w * 2 + kc) * 64 + lane) * 8);
            acc = __builtin_amdgcn_mfma_f32_16x16x32_bf16(a, b, acc, 0, 0, 0);
        }
        if (qd == 0) {
            const int n = w * 16 + m16;
            const float bn = bout[n];
#pragma unroll
            for (int r = 0; r < 4; r++) xs4[r][n] = acc[r] + bn;
        }
    }
    __syncthreads();

    // ---- LN1 (wave w = query w); residual qf; store x1 ----
    {
        const float xpre = qf + xs4[w][lane];
        float s = xpre, s2 = xpre * xpre;
#pragma unroll
        for (int o = 32; o >= 1; o >>= 1) {
            s += __shfl_xor(s, o, 64);
            s2 += __shfl_xor(s2, o, 64);
        }
        const float mean = s * (1.f / 64.f);
        const float var = s2 * (1.f / 64.f) - mean * mean;
        const float xn = (xpre - mean) * rsqrtf(var + 1e-5f);
        xout[(size_t)qi * DM + lane] = xn * g1[lane] + b1[lane];
    }
}

// ---- kernel 4: FFN via MFMA, 32 queries/block, hidden in 4 quarters ----
// GEMM1 swapped: D = W1^T * x^T -> lane holds 4 consecutive hidden values of one
// query -> packed ds_write_b64 into hb[query][hidden] (GEMM2 A-reads unchanged).
// x staged once in B-frag layout (4 ds_read_b128 total). ~28.6 KB LDS.
__global__ void __launch_bounds__(256)
ffn_kernel(const __hip_bfloat16* __restrict__ W1p, const float* __restrict__ bff1,
           const __hip_bfloat16* __restrict__ W2p, const float* __restrict__ bff2,
           const float* __restrict__ g2, const float* __restrict__ b2,
           float* __restrict__ io) {
    __shared__ __align__(16) __hip_bfloat16 xq[2][2][64][8];  // x B-frags: [ntile][kc]
    __shared__ __align__(16) __hip_bfloat16 hb[32][264];      // 16896 B (256 cols + pad)
    __shared__ __align__(16) float yr[32][64];                // 8192 B

    const int tid = threadIdx.x;
    const int lane = tid & 63;
    const int w = tid >> 6;
    const int m16 = lane & 15, qd = lane >> 4;
    const int q0 = blockIdx.x * 32;

    // ---- load x1 -> B-frag layout: thread t -> query t>>3, model dims (t&7)*8..+7
    {
        const int q = tid >> 3, i = tid & 7;
        const float4 v0 = *(const float4*)&io[(size_t)(q0 + q) * DM + i * 8];
        const float4 v1 = *(const float4*)&io[(size_t)(q0 + q) * DM + i * 8 + 4];
        uint2 ua, ub;
        ua.x = f2bf_bits(v0.x) | (f2bf_bits(v0.y) << 16);
        ua.y = f2bf_bits(v0.z) | (f2bf_bits(v0.w) << 16);
        ub.x = f2bf_bits(v1.x) | (f2bf_bits(v1.y) << 16);
        ub.y = f2bf_bits(v1.z) | (f2bf_bits(v1.w) << 16);
        uint4 u4 = {ua.x, ua.y, ub.x, ub.y};
        *(uint4*)&xq[q >> 4][i >> 2][(q & 15) + (i & 3) * 16][0] = u4;
    }
    __syncthreads();

    // x B-frags: loop-invariant, load once (4 ds_read_b128)
    short8 bx[2][2];
#pragma unroll
    for (int nt = 0; nt < 2; nt++)
#pragma unroll
        for (int kc = 0; kc < 2; kc++)
            bx[nt][kc] = *(const short8*)&xq[nt][kc][lane][0];

    f32x4 yacc[2];
    yacc[0] = (f32x4){0.f, 0.f, 0.f, 0.f};
    yacc[1] = (f32x4){0.f, 0.f, 0.f, 0.f};

#pragma unroll
    for (int qtr = 0; qtr < 4; qtr++) {
        // GEMM1 quarter (swapped): hidden m-tiles; wave w does htl = mt*4 + w
#pragma unroll
        for (int mt = 0; mt < 4; mt++) {
            const int htl = mt * 4 + w;            // 0..15 within quarter
            const int ht = qtr * 16 + htl;         // global hidden tile
            f32x4 acc[2];
            acc[0] = (f32x4){0.f, 0.f, 0.f, 0.f};
            acc[1] = (f32x4){0.f, 0.f, 0.f, 0.f};
#pragma unroll
            for (int kc = 0; kc < 2; kc++) {
                const short8 a = *(const short8*)(W1p + ((size_t)(ht * 2 + kc) * 64 + lane) * 8);
#pragma unroll
                for (int nt = 0; nt < 2; nt++)
                    acc[nt] = __builtin_amdgcn_mfma_f32_16x16x32_bf16(a, bx[nt][kc], acc[nt], 0, 0, 0);
            }
            const float4 b4 = *(const float4*)&bff1[ht * 16 + qd * 4];
#pragma unroll
            for (int nt = 0; nt < 2; nt++) {
                const float r0 = fmaxf(acc[nt][0] + b4.x, 0.f);
                const float r1 = fmaxf(acc[nt][1] + b4.y, 0.f);
                const float r2 = fmaxf(acc[nt][2] + b4.z, 0.f);
                const float r3 = fmaxf(acc[nt][3] + b4.w, 0.f);
                uint2 u;
                u.x = f2bf_bits(r0) | (f2bf_bits(r1) << 16);
                u.y = f2bf_bits(r2) | (f2bf_bits(r3) << 16);
                *(uint2*)&hb[nt * 16 + m16][htl * 16 + qd * 4] = u;
            }
        }
        __syncthreads();
        // GEMM2 partial: wave w owns y-ntile w; this quarter's 8 kchunks
#pragma unroll
        for (int kc2 = 0; kc2 < 8; kc2++) {
            const short8 b = *(const short8*)(W2p + ((size_t)(w * 32 + qtr * 8 + kc2) * 64 + lane) * 8);
#pragma unroll
            for (int mt = 0; mt < 2; mt++) {
                const short8 a = *(const short8*)&hb[mt * 16 + m16][kc2 * 32 + qd * 8];
                yacc[mt] = __builtin_amdgcn_mfma_f32_16x16x32_bf16(a, b, yacc[mt], 0, 0, 0);
            }
        }
        __syncthreads();   // hb consumed before next quarter overwrites
    }

    // ---- Y + bff2 (x1 residual re-read from io at LN stage) ----
    {
        const int n = w * 16 + m16;
        const float bn = bff2[n];
#pragma unroll
        for (int mt = 0; mt < 2; mt++)
#pragma unroll
            for (int r = 0; r < 4; r++) {
                const int mm = mt * 16 + qd * 4 + r;
                yr[mm][n] = yacc[mt][r] + bn;
            }
    }
    __syncthreads();

    // ---- LN2 + store: thread t -> query t>>3, cols (t&7)*8..+7; 8-lane reduce ----
    {
        const int q = tid >> 3, i = tid & 7;
        const float4 x0 = *(const float4*)&io[(size_t)(q0 + q) * DM + i * 8];
        const float4 x1 = *(const float4*)&io[(size_t)(q0 + q) * DM + i * 8 + 4];
        float4 v0 = *(const float4*)&yr[q][i * 8];
        float4 v1 = *(const float4*)&yr[q][i * 8 + 4];
        v0.x += x0.x; v0.y += x0.y; v0.z += x0.z; v0.w += x0.w;
        v1.x += x1.x; v1.y += x1.y; v1.z += x1.z; v1.w += x1.w;
        float s = v0.x + v0.y + v0.z + v0.w + v1.x + v1.y + v1.z + v1.w;
        float s2 = v0.x * v0.x + v0.y * v0.y + v0.z * v0.z + v0.w * v0.w
                 + v1.x * v1.x + v1.y * v1.y + v1.z * v1.z + v1.w * v1.w;
#pragma unroll
        for (int o = 4; o >= 1; o >>= 1) { s += __shfl_xor(s, o, 64); s2 += __shfl_xor(s2, o, 64); }
        const float mean = s * (1.f / 64.f);
        const float var = s2 * (1.f / 64.f) - mean * mean;
        const float rstd = rsqrtf(var + 1e-5f);
        const float4 ga = *(const float4*)&g2[i * 8];
        const float4 gb = *(const float4*)&g2[i * 8 + 4];
        const float4 ba4 = *(const float4*)&b2[i * 8];
        const float4 bb4 = *(const float4*)&b2[i * 8 + 4];
        float4 o0, o1;
        o0.x = (v0.x - mean) * rstd * ga.x + ba4.x;
        o0.y = (v0.y - mean) * rstd * ga.y + ba4.y;
        o0.z = (v0.z - mean) * rstd * ga.z + ba4.z;
        o0.w = (v0.w - mean) * rstd * ga.w + ba4.w;
        o1.x = (v1.x - mean) * rstd * gb.x + bb4.x;
        o1.y = (v1.y - mean) * rstd * gb.y + bb4.y;
        o1.z = (v1.z - mean) * rstd * gb.z + bb4.z;
        o1.w = (v1.w - mean) * rstd * gb.w + bb4.w;
        *(float4*)&io[(size_t)(q0 + q) * DM + i * 8] = o0;
        *(float4*)&io[(size_t)(q0 + q) * DM + i * 8 + 4] = o1;
    }
}

extern "C" void kernel_launch(void* const* d_in, const int* in_sizes, int n_in,
                              void* d_out, int out_size, void* d_ws, size_t ws_size,
                              hipStream_t stream) {
    const int B0 = (in_sizes[4] >= 4096) ? 4 : 6;   // int side-inputs present -> 6
    const float* q_feat = (const float*)d_in[0];
    const float* dvf    = (const float*)d_in[1];
    const float* refp   = (const float*)d_in[2];
    const float* q_pos  = (const float*)d_in[3];
    const float* Wv   = (const float*)d_in[B0 + 0];
    const float* bv   = (const float*)d_in[B0 + 1];
    const float* Wo   = (const float*)d_in[B0 + 2];
    const float* bo   = (const float*)d_in[B0 + 3];
    const float* Wa   = (const float*)d_in[B0 + 4];
    const float* ba   = (const float*)d_in[B0 + 5];
    const float* Wout = (const float*)d_in[B0 + 6];
    const float* bout = (const float*)d_in[B0 + 7];
    const float* g1   = (const float*)d_in[B0 + 8];
    const float* b1   = (const float*)d_in[B0 + 9];
    const float* W1   = (const float*)d_in[B0 + 10];
    const float* bff1 = (const float*)d_in[B0 + 11];
    const float* W2   = (const float*)d_in[B0 + 12];
    const float* bff2 = (const float*)d_in[B0 + 13];
    const float* g2   = (const float*)d_in[B0 + 14];
    const float* b2   = (const float*)d_in[B0 + 15];
    float* out = (float*)d_out;

    const size_t val_elems = (size_t)LIN * DM;
    const size_t pack_elems = (size_t)(128 + 128 + 60 + 8) * 64 * 8;   // 165888 bf16
    const size_t PAD_ELEMS = 12288;    // guard pad: derived OOB corners read here x0
    const bool dbuf = ws_size >= (pack_elems + 2 * val_elems + PAD_ELEMS) * sizeof(__hip_bfloat16);

    __hip_bfloat16* W1p = (__hip_bfloat16*)d_ws;
    __hip_bfloat16* W2p = W1p + (size_t)128 * 64 * 8;
    __hip_bfloat16* Woap = W2p + (size_t)128 * 64 * 8;
    __hip_bfloat16* Woutp = Woap + (size_t)60 * 64 * 8;
    __hip_bfloat16* val0 = W1p + pack_elems;
    __hip_bfloat16* val1 = dbuf ? val0 + val_elems : val0;
    __hip_bfloat16* pad_ptr = val1 + val_elems;

    if (dbuf) {
        prep_kernel<<<82 + (2 * LIN + 63) / 64, 256, 0, stream>>>(
            dvf, Wv, bv, W1, W2, Wo, Wa, Wout,
            W1p, W2p, Woap, Woutp, val0, val1, pad_ptr, 2 * LIN);
        attn4_kernel<<<(NB * NQ) / 4, 256, 0, stream>>>(
            q_feat, refp, q_pos, Woap, bo, ba, Woutp, bout, g1, b1,
            val0, val1, 0, out);
    } else {
        for (int b = 0; b < NB; b++) {
            prep_kernel<<<82 + (LIN + 63) / 64, 256, 0, stream>>>(
                dvf + (size_t)b * val_elems, Wv, bv, W1, W2, Wo, Wa, Wout,
                W1p, W2p, Woap, Woutp, val0, val0, pad_ptr, LIN);
            attn4_kernel<<<NQ / 4, 256, 0, stream>>>(
                q_feat, refp, q_pos, Woap, bo, ba, Woutp, bout, g1, b1,
                val0, val0, b * NQ, out);
        }
    }
    ffn_kernel<<<(NB * NQ) / 32, 256, 0, stream>>>(W1p, bff1, W2p, bff2, g2, b2, out);
}